// Round 3
// baseline (2873.726 us; speedup 1.0000x reference)
//
#include <hip/hip_runtime.h>
#include <hip/hip_bf16.h>

typedef unsigned short ush;
typedef unsigned int uint32;

#define NB 16
#define NT 128
#define NTM 128
#define NV 25
#define NCIN 64
#define NCM 256
#define NH 8
#define ND 32
#define NC 256
#define NK 3
#define NKC 768
#define LN_EPS 1e-6f
#define QSCALE 0.17677669529663687f

__device__ __forceinline__ float bf2f(ush u) {
    union { uint32 i; float f; } x; x.i = ((uint32)u) << 16; return x.f;
}
__device__ __forceinline__ ush f2bf(float f) {
    union { float f; uint32 i; } x; x.f = f;
    uint32 r = x.i + 0x7FFFu + ((x.i >> 16) & 1u);
    return (ush)(r >> 16);
}
__device__ __forceinline__ void unpack8(uint4 u, float* dst) {
    dst[0] = bf2f((ush)(u.x & 0xffff)); dst[1] = bf2f((ush)(u.x >> 16));
    dst[2] = bf2f((ush)(u.y & 0xffff)); dst[3] = bf2f((ush)(u.y >> 16));
    dst[4] = bf2f((ush)(u.z & 0xffff)); dst[5] = bf2f((ush)(u.z >> 16));
    dst[6] = bf2f((ush)(u.w & 0xffff)); dst[7] = bf2f((ush)(u.w >> 16));
}

// -------- dtype detector: low-half-word exponent field statistics --------
__global__ __launch_bounds__(256) void k_detect(const uint32* __restrict__ xw,
                                               int* __restrict__ flag)
{
    __shared__ int cnt;
    if (threadIdx.x == 0) cnt = 0;
    __syncthreads();
    int c = 0;
    for (int i = 0; i < 4; ++i) {
        uint32 u = xw[threadIdx.x + 256 * i];
        uint32 e = (u >> 7) & 0xFF;
        c += (e >= 100 && e <= 135) ? 1 : 0;
    }
    atomicAdd(&cnt, c);
    __syncthreads();
    if (threadIdx.x == 0) *flag = (cnt > 700) ? 1 : 0;   // 1 = bf16, 0 = f32
}

__global__ __launch_bounds__(256) void k_convert(const void* __restrict__ src,
                                                 ush* __restrict__ dst, int n,
                                                 const int* __restrict__ flag)
{
    const bool isbf = (*flag != 0);
    for (int i = blockIdx.x * 256 + threadIdx.x; i < n; i += gridDim.x * 256) {
        dst[i] = isbf ? ((const ush*)src)[i] : f2bf(((const float*)src)[i]);
    }
}

// ---------------- stage 1: causal temporal self-attention per (b,h,v) ----------------
__global__ __launch_bounds__(256) void k_stage1(
    const ush* __restrict__ x, const ush* __restrict__ Wq,
    const ush* __restrict__ Wk, const ush* __restrict__ Wv,
    ush* __restrict__ h1)
{
    const int v = blockIdx.x, h = blockIdx.y, b = blockIdx.z;
    const int tid = threadIdx.x;
    __shared__ ush xs[NT * NCIN];                 // 16 KB
    __shared__ float wq[NCIN * ND], wk[NCIN * ND], wv[NCIN * ND]; // 24 KB
    __shared__ float qs[NT * ND];                 // 16 KB
    __shared__ float ks[NT * 33], vs[NT * 33];    // 33 KB (pad 33 -> conflict-free)
    __shared__ float plds[4][NT];                 // 2 KB

    const ush* xg = x + ((size_t)b * NT * NV + v) * NCIN;
    for (int i = tid; i < NT * NCIN / 8; i += 256) {
        int t = i >> 3, c8 = (i & 7) * 8;
        *(uint4*)&xs[t * NCIN + c8] = *(const uint4*)&xg[(size_t)t * NV * NCIN + c8];
    }
    for (int i = tid; i < NCIN * ND / 8; i += 256) {
        int c = i >> 2, d8 = (i & 3) * 8;
        uint4 uq = *(const uint4*)&Wq[(size_t)c * NC + h * ND + d8];
        uint4 uk = *(const uint4*)&Wk[(size_t)c * NC + h * ND + d8];
        uint4 uv = *(const uint4*)&Wv[(size_t)c * NC + h * ND + d8];
        unpack8(uq, &wq[c * ND + d8]);
        unpack8(uk, &wk[c * ND + d8]);
        unpack8(uv, &wv[c * ND + d8]);
    }
    __syncthreads();
    {   // projection: thread (d = tid&31, tg = tid>>5) computes 16 t rows
        const int d = tid & 31, tg = tid >> 5;
        for (int i = 0; i < 16; ++i) {
            const int t = tg * 16 + i;
            float aq = 0.f, ak = 0.f, av = 0.f;
            #pragma unroll 8
            for (int c = 0; c < NCIN; ++c) {
                float xv = bf2f(xs[t * NCIN + c]);
                aq += xv * wq[c * ND + d];
                ak += xv * wk[c * ND + d];
                av += xv * wv[c * ND + d];
            }
            qs[t * ND + d] = aq * QSCALE;
            ks[t * 33 + d] = ak;
            vs[t * 33 + d] = av;
        }
    }
    __syncthreads();
    {   // attention: wave w handles rows t = w + 4i
        const int w = tid >> 6, lane = tid & 63;
        const int half = lane >> 5, dd = lane & 31;
        ush* og = h1 + ((size_t)b * NT * NV + v) * NC + h * ND;
        for (int i = 0; i < 32; ++i) {
            const int t = w + 4 * i;
            float a0 = 0.f, a1 = 0.f;
            #pragma unroll 8
            for (int c = 0; c < ND; ++c) {
                float qv = qs[t * ND + c];
                a0 += qv * ks[lane * 33 + c];
                a1 += qv * ks[(lane + 64) * 33 + c];
            }
            float sc0 = (lane <= t) ? a0 : -1e30f;
            float sc1 = (lane + 64 <= t) ? a1 : -1e30f;
            float mx = fmaxf(sc0, sc1);
            #pragma unroll
            for (int o = 32; o; o >>= 1) mx = fmaxf(mx, __shfl_xor(mx, o));
            float e0 = (lane <= t) ? __expf(sc0 - mx) : 0.f;
            float e1 = (lane + 64 <= t) ? __expf(sc1 - mx) : 0.f;
            float sm = e0 + e1;
            #pragma unroll
            for (int o = 32; o; o >>= 1) sm += __shfl_xor(sm, o);
            plds[w][lane] = e0;
            plds[w][lane + 64] = e1;
            __syncthreads();   // uniform loop -> legal; makes plds writes visible
            float acc = 0.f;
            const int sb = half * 64;
            #pragma unroll 8
            for (int j = 0; j < 64; ++j)
                acc += plds[w][sb + j] * vs[(sb + j) * 33 + dd];
            acc += __shfl_xor(acc, 32);
            if (lane < 32) og[(size_t)t * NV * NC + dd] = f2bf(acc / sm);
        }
    }
}

// ---------------- row LayerNorm (unbiased std), in place, 1 wave = 1 row ----------------
__global__ __launch_bounds__(256) void k_ln(
    ush* __restrict__ buf, const ush* __restrict__ g, const ush* __restrict__ bb)
{
    const int row = blockIdx.x * 4 + (threadIdx.x >> 6);
    const int lane = threadIdx.x & 63;
    ush* p = buf + (size_t)row * NC + lane * 4;
    uint2 u = *(uint2*)p;
    float x0 = bf2f((ush)(u.x & 0xffff)), x1 = bf2f((ush)(u.x >> 16));
    float x2 = bf2f((ush)(u.y & 0xffff)), x3 = bf2f((ush)(u.y >> 16));
    float s = x0 + x1 + x2 + x3;
    float q = x0 * x0 + x1 * x1 + x2 * x2 + x3 * x3;
    #pragma unroll
    for (int o = 32; o; o >>= 1) { s += __shfl_xor(s, o); q += __shfl_xor(q, o); }
    float mean = s * (1.f / 256.f);
    float var = fmaxf((q - 256.f * mean * mean) * (1.f / 255.f), 0.f);
    float inv = 1.f / (sqrtf(var) + LN_EPS);
    float o0 = bf2f(g[lane * 4 + 0]) * (x0 - mean) * inv + bf2f(bb[lane * 4 + 0]);
    float o1 = bf2f(g[lane * 4 + 1]) * (x1 - mean) * inv + bf2f(bb[lane * 4 + 1]);
    float o2 = bf2f(g[lane * 4 + 2]) * (x2 - mean) * inv + bf2f(bb[lane * 4 + 2]);
    float o3 = bf2f(g[lane * 4 + 3]) * (x3 - mean) * inv + bf2f(bb[lane * 4 + 3]);
    uint32 lo = (uint32)f2bf(o0) | ((uint32)f2bf(o1) << 16);
    uint32 hi = (uint32)f2bf(o2) | ((uint32)f2bf(o3) << 16);
    *(uint2*)p = make_uint2(lo, hi);
}

// ---------------- K/V projections of memory m ----------------
__global__ __launch_bounds__(256) void k_projkv(
    const ush* __restrict__ m, const ush* __restrict__ Wk, const ush* __restrict__ Wv,
    ush* __restrict__ k2, ush* __restrict__ v2)
{
    const int mat = blockIdx.x >> 2;
    const int oc0 = (blockIdx.x & 3) * 64;
    const int tok0 = blockIdx.y * 64;
    const ush* W = mat ? Wv : Wk;
    ush* outp = mat ? v2 : k2;
    __shared__ ush ms[64][72], ws[64][72];
    const int tid = threadIdx.x;
    const int tx = tid & 15, ty = tid >> 4;
    float acc[4][4] = {};
    for (int kc = 0; kc < 256; kc += 64) {
        __syncthreads();
        for (int i = tid; i < 512; i += 256) {
            int r = i >> 3, c8 = (i & 7) * 8;
            *(uint4*)&ms[r][c8] = *(const uint4*)&m[((size_t)tok0 + r) * NC + kc + c8];
            *(uint4*)&ws[r][c8] = *(const uint4*)&W[((size_t)kc + r) * NC + oc0 + c8];
        }
        __syncthreads();
        #pragma unroll 4
        for (int k = 0; k < 64; ++k) {
            float a[4], b4[4];
            #pragma unroll
            for (int j = 0; j < 4; ++j) a[j] = bf2f(ms[ty * 4 + j][k]);
            #pragma unroll
            for (int j = 0; j < 4; ++j) b4[j] = bf2f(ws[k][tx * 4 + j]);
            #pragma unroll
            for (int i2 = 0; i2 < 4; ++i2)
                #pragma unroll
                for (int j = 0; j < 4; ++j)
                    acc[i2][j] += a[i2] * b4[j];
        }
    }
    #pragma unroll
    for (int i2 = 0; i2 < 4; ++i2) {
        ush* o = outp + ((size_t)tok0 + ty * 4 + i2) * NC + oc0 + tx * 4;
        uint32 lo = (uint32)f2bf(acc[i2][0]) | ((uint32)f2bf(acc[i2][1]) << 16);
        uint32 hi = (uint32)f2bf(acc[i2][2]) | ((uint32)f2bf(acc[i2][3]) << 16);
        *(uint2*)o = make_uint2(lo, hi);
    }
}

// ---------------- stage 2: cross-attention vs memory per (b,h,v) ----------------
__global__ __launch_bounds__(256) void k_stage2(
    const ush* __restrict__ h1, const ush* __restrict__ Wq2,
    const ush* __restrict__ k2g, const ush* __restrict__ v2g,
    ush* __restrict__ h2)
{
    const int v = blockIdx.x, h = blockIdx.y, b = blockIdx.z;
    const int tid = threadIdx.x;
    __shared__ ush hs[NT * NC];                  // 64 KB
    __shared__ ush w2[NC * ND];                  // 16 KB
    __shared__ float qs[NT * ND];                // 16 KB
    __shared__ float ks[NT * 33], vs[NT * 33];   // 33 KB
    __shared__ float plds[4][NTM];               // 2 KB

    const ush* hgg = h1 + ((size_t)b * NT * NV + v) * NC;
    for (int i = tid; i < NT * NC / 8; i += 256) {
        int t = i >> 5, c8 = (i & 31) * 8;
        *(uint4*)&hs[t * NC + c8] = *(const uint4*)&hgg[(size_t)t * NV * NC + c8];
    }
    for (int i = tid; i < NC * ND / 8; i += 256) {
        int c = i >> 2, d8 = (i & 3) * 8;
        *(uint4*)&w2[c * ND + d8] = *(const uint4*)&Wq2[(size_t)c * NC + h * ND + d8];
    }
    const ush* kg = k2g + ((size_t)b * NTM * NV + v) * NC + h * ND;
    const ush* vg = v2g + ((size_t)b * NTM * NV + v) * NC + h * ND;
    for (int i = tid; i < NTM * ND / 8; i += 256) {
        int s2 = i >> 2, d8 = (i & 3) * 8;
        uint4 ku = *(const uint4*)&kg[(size_t)s2 * NV * NC + d8];
        uint4 vu = *(const uint4*)&vg[(size_t)s2 * NV * NC + d8];
        unpack8(ku, &ks[s2 * 33 + d8]);
        unpack8(vu, &vs[s2 * 33 + d8]);
    }
    __syncthreads();
    {   // q2 projection, K = 256
        const int d = tid & 31, tg = tid >> 5;
        float acc[16];
        #pragma unroll
        for (int i = 0; i < 16; ++i) acc[i] = 0.f;
        for (int c = 0; c < NC; ++c) {
            float wvv = bf2f(w2[c * ND + d]);
            #pragma unroll
            for (int i = 0; i < 16; ++i)
                acc[i] += bf2f(hs[(tg * 16 + i) * NC + c]) * wvv;
        }
        #pragma unroll
        for (int i = 0; i < 16; ++i) qs[(tg * 16 + i) * ND + d] = acc[i] * QSCALE;
    }
    __syncthreads();
    {
        const int w = tid >> 6, lane = tid & 63;
        const int half = lane >> 5, dd = lane & 31;
        ush* og = h2 + ((size_t)b * NT * NV + v) * NC + h * ND;
        for (int i = 0; i < 32; ++i) {
            const int t = w + 4 * i;
            float a0 = 0.f, a1 = 0.f;
            #pragma unroll 8
            for (int c = 0; c < ND; ++c) {
                float qv = qs[t * ND + c];
                a0 += qv * ks[lane * 33 + c];
                a1 += qv * ks[(lane + 64) * 33 + c];
            }
            float mx = fmaxf(a0, a1);
            #pragma unroll
            for (int o = 32; o; o >>= 1) mx = fmaxf(mx, __shfl_xor(mx, o));
            float e0 = __expf(a0 - mx), e1 = __expf(a1 - mx);
            float sm = e0 + e1;
            #pragma unroll
            for (int o = 32; o; o >>= 1) sm += __shfl_xor(sm, o);
            plds[w][lane] = e0; plds[w][lane + 64] = e1;
            __syncthreads();   // uniform loop -> legal
            float acc = 0.f;
            const int sb = half * 64;
            #pragma unroll 8
            for (int j = 0; j < 64; ++j)
                acc += plds[w][sb + j] * vs[(sb + j) * 33 + dd];
            acc += __shfl_xor(acc, 32);
            if (lane < 32) og[(size_t)t * NV * NC + dd] = f2bf(acc / sm);
        }
    }
}

// ---------------- stage 3: Wg expansion + GCN contraction + LayerNorm, f32 output ----------------
__global__ __launch_bounds__(256) void k_stage3(
    const ush* __restrict__ h2, const ush* __restrict__ Wg, const ush* __restrict__ bg,
    const ush* __restrict__ A, const ush* __restrict__ g3, const ush* __restrict__ b3,
    float* __restrict__ outp)
{
    const int t = blockIdx.x, b = blockIdx.y;
    const int tid = threadIdx.x;
    __shared__ char smem[61952];
    ush* hs = (ush*)smem;                  // [25*256] bf16 (phase A)
    ush* wgs = (ush*)(smem + 12800);       // [32*768] bf16 (phase A)
    float* As = (float*)smem;              // [1875] f32 (phase B, reuses hs)
    float* h3s = (float*)(smem + 7504);    // [25*256] f32 (phase B/C, reuses wgs)

    const ush* hg = h2 + ((size_t)(b * NT + t)) * NV * NC;
    for (int i = tid; i < NV * NC / 8; i += 256)
        *(uint4*)&hs[i * 8] = *(const uint4*)&hg[i * 8];

    float acc[75];
    #pragma unroll
    for (int j = 0; j < 75; ++j) acc[j] = bf2f(bg[(j % 3) * 256 + tid]);

    for (int ci0 = 0; ci0 < 256; ci0 += 32) {
        __syncthreads();
        for (int i = tid; i < 32 * 768 / 8; i += 256) {
            int r = i / 96, c8 = (i % 96) * 8;
            *(uint4*)&wgs[r * 768 + c8] = *(const uint4*)&Wg[(size_t)(ci0 + r) * NKC + c8];
        }
        __syncthreads();
        for (int ci = 0; ci < 32; ++ci) {
            float w0 = bf2f(wgs[ci * 768 + tid]);
            float w1 = bf2f(wgs[ci * 768 + 256 + tid]);
            float w2v = bf2f(wgs[ci * 768 + 512 + tid]);
            #pragma unroll
            for (int vv = 0; vv < 25; ++vv) {
                float xv = bf2f(hs[vv * 256 + ci0 + ci]);
                acc[vv * 3 + 0] += xv * w0;
                acc[vv * 3 + 1] += xv * w1;
                acc[vv * 3 + 2] += xv * w2v;
            }
        }
    }
    __syncthreads();
    for (int i = tid; i < NK * NV * NV; i += 256) As[i] = bf2f(A[i]);
    __syncthreads();
    for (int w = 0; w < NV; ++w) {
        float a = 0.f;
        #pragma unroll
        for (int k = 0; k < NK; ++k)
            #pragma unroll
            for (int vv = 0; vv < NV; ++vv)
                a += As[k * 625 + vv * 25 + w] * acc[vv * 3 + k];
        h3s[w * 256 + tid] = a;
    }
    __syncthreads();
    {   // LayerNorm rows + f32 output
        const int wv = tid >> 6, lane = tid & 63;
        for (int w = wv; w < NV; w += 4) {
            float x0 = h3s[w * 256 + lane * 4 + 0];
            float x1 = h3s[w * 256 + lane * 4 + 1];
            float x2 = h3s[w * 256 + lane * 4 + 2];
            float x3 = h3s[w * 256 + lane * 4 + 3];
            float s = x0 + x1 + x2 + x3;
            float q = x0 * x0 + x1 * x1 + x2 * x2 + x3 * x3;
            #pragma unroll
            for (int o = 32; o; o >>= 1) { s += __shfl_xor(s, o); q += __shfl_xor(q, o); }
            float mean = s * (1.f / 256.f);
            float var = fmaxf((q - 256.f * mean * mean) * (1.f / 255.f), 0.f);
            float inv = 1.f / (sqrtf(var) + LN_EPS);
            float o0 = bf2f(g3[lane * 4 + 0]) * (x0 - mean) * inv + bf2f(b3[lane * 4 + 0]);
            float o1 = bf2f(g3[lane * 4 + 1]) * (x1 - mean) * inv + bf2f(b3[lane * 4 + 1]);
            float o2 = bf2f(g3[lane * 4 + 2]) * (x2 - mean) * inv + bf2f(b3[lane * 4 + 2]);
            float o3 = bf2f(g3[lane * 4 + 3]) * (x3 - mean) * inv + bf2f(b3[lane * 4 + 3]);
            float* op = outp + (((size_t)(b * NT + t)) * NV + w) * NC + lane * 4;
            *(float4*)op = make_float4(o0, o1, o2, o3);
        }
    }
}

extern "C" void kernel_launch(void* const* d_in, const int* in_sizes, int n_in,
                              void* d_out, int out_size, void* d_ws, size_t ws_size,
                              hipStream_t stream)
{
    const size_t NTOK = (size_t)NB * NT * NV;   // 51200
    char* ws = (char*)d_ws;
    int* flag = (int*)ws;
    ush* h1 = (ush*)(ws + 256);
    ush* k2 = h1 + NTOK * NC;
    ush* v2 = k2 + NTOK * NC;
    ush* h2 = v2 + NTOK * NC;
    ush* conv = h2 + NTOK * NC;   // canonical bf16 input copies start here

    const int sz[18] = { NB*NT*NV*NCIN, NB*NTM*NV*NCM, NK*NV*NV, 0,
                         NCIN*NC, NCIN*NC, NCIN*NC, NC, NC,
                         NC*NC, NCM*NC, NCM*NC, NC, NC,
                         NC*NKC, NKC, NC, NC };
    size_t conv_elems = 0;
    for (int i = 0; i < 18; ++i) if (i != 3) conv_elems += (size_t)((sz[i] + 7) & ~7);
    const size_t need = 256 + 4 * NTOK * NC * sizeof(ush) + conv_elems * sizeof(ush);

    const ush* cin[18];
    if (ws_size >= need) {
        k_detect<<<1, 256, 0, stream>>>((const uint32*)d_in[0], flag);
        ush* p = conv;
        for (int i = 0; i < 18; ++i) {
            if (i == 3) { cin[i] = nullptr; continue; }
            int n = sz[i];
            int blocks = (n + 255) / 256; if (blocks > 4096) blocks = 4096;
            k_convert<<<blocks, 256, 0, stream>>>(d_in[i], p, n, flag);
            cin[i] = p;
            p += (size_t)((n + 7) & ~7);
        }
    } else {
        for (int i = 0; i < 18; ++i) cin[i] = (const ush*)d_in[i];  // assume bf16
    }

    const ush* x   = cin[0];
    const ush* m   = cin[1];
    const ush* A   = cin[2];
    const ush* Wq1 = cin[4];
    const ush* Wk1 = cin[5];
    const ush* Wv1 = cin[6];
    const ush* g1  = cin[7];
    const ush* b1  = cin[8];
    const ush* Wq2 = cin[9];
    const ush* Wk2 = cin[10];
    const ush* Wv2 = cin[11];
    const ush* g2  = cin[12];
    const ush* b2  = cin[13];
    const ush* Wg  = cin[14];
    const ush* bg  = cin[15];
    const ush* g3  = cin[16];
    const ush* b3  = cin[17];
    float* out = (float*)d_out;

    k_stage1<<<dim3(NV, NH, NB), 256, 0, stream>>>(x, Wq1, Wk1, Wv1, h1);
    k_ln<<<NTOK / 4, 256, 0, stream>>>(h1, g1, b1);
    k_projkv<<<dim3(8, 800), 256, 0, stream>>>(m, Wk2, Wv2, k2, v2);
    k_stage2<<<dim3(NV, NH, NB), 256, 0, stream>>>(h1, Wq2, k2, v2, h2);
    k_ln<<<NTOK / 4, 256, 0, stream>>>(h2, g2, b2);
    k_stage3<<<dim3(NT, NB), 256, 0, stream>>>(h2, Wg, bg, A, g3, b3, out);
}

// Round 4
// 1368.111 us; speedup vs baseline: 2.1005x; 2.1005x over previous
//
#include <hip/hip_runtime.h>
#include <hip/hip_bf16.h>

typedef unsigned short ush;
typedef unsigned int uint32;
typedef __attribute__((ext_vector_type(8))) short s8v;   // 8 bf16 (4 VGPRs)
typedef __attribute__((ext_vector_type(4))) float f4v;   // MFMA accumulator

#define NB 16
#define NT 128
#define NTM 128
#define NV 25
#define NCIN 64
#define NCM 256
#define NH 8
#define ND 32
#define NC 256
#define NK 3
#define NKC 768
#define LN_EPS 1e-6f
#define QSCALE 0.17677669529663687f

__device__ __forceinline__ float bf2f(ush u) {
    union { uint32 i; float f; } x; x.i = ((uint32)u) << 16; return x.f;
}
__device__ __forceinline__ ush f2bf(float f) {
    union { float f; uint32 i; } x; x.f = f;
    uint32 r = x.i + 0x7FFFu + ((x.i >> 16) & 1u);
    return (ush)(r >> 16);
}
__device__ __forceinline__ void unpack8(uint4 u, float* dst) {
    dst[0] = bf2f((ush)(u.x & 0xffff)); dst[1] = bf2f((ush)(u.x >> 16));
    dst[2] = bf2f((ush)(u.y & 0xffff)); dst[3] = bf2f((ush)(u.y >> 16));
    dst[4] = bf2f((ush)(u.z & 0xffff)); dst[5] = bf2f((ush)(u.z >> 16));
    dst[6] = bf2f((ush)(u.w & 0xffff)); dst[7] = bf2f((ush)(u.w >> 16));
}

// -------- dtype detector (f32 vs bf16 device buffers) --------
__global__ __launch_bounds__(256) void k_detect(const uint32* __restrict__ xw,
                                               int* __restrict__ flag)
{
    __shared__ int cnt;
    if (threadIdx.x == 0) cnt = 0;
    __syncthreads();
    int c = 0;
    for (int i = 0; i < 4; ++i) {
        uint32 u = xw[threadIdx.x + 256 * i];
        uint32 e = (u >> 7) & 0xFF;
        c += (e >= 100 && e <= 135) ? 1 : 0;
    }
    atomicAdd(&cnt, c);
    __syncthreads();
    if (threadIdx.x == 0) *flag = (cnt > 700) ? 1 : 0;   // 1 = bf16, 0 = f32
}

__global__ __launch_bounds__(256) void k_convert(const void* __restrict__ src,
                                                 ush* __restrict__ dst, int n,
                                                 const int* __restrict__ flag)
{
    const bool isbf = (*flag != 0);
    for (int i = blockIdx.x * 256 + threadIdx.x; i < n; i += gridDim.x * 256) {
        dst[i] = isbf ? ((const ush*)src)[i] : f2bf(((const float*)src)[i]);
    }
}

// transpose-convert: src [K,N] (f32 or bf16) -> dst [N,K] bf16
__global__ __launch_bounds__(256) void k_convT(const void* __restrict__ src,
                                               ush* __restrict__ dst, int K, int N,
                                               const int* __restrict__ flag)
{
    const bool isbf = (*flag != 0);
    int idx = blockIdx.x * 256 + threadIdx.x;
    if (idx >= K * N) return;
    int n = idx / K, k = idx - n * K;
    dst[idx] = isbf ? ((const ush*)src)[k * N + n] : f2bf(((const float*)src)[k * N + n]);
}

// -------- generic MFMA GEMM: C[M,N] = A[M,K] @ Bt[N,K]^T, all bf16 --------
// BM=BN=64, BK=64, 4 waves; XOR-swizzled LDS rows (128B), 16x16x32 bf16 MFMA.
__global__ __launch_bounds__(256) void k_gemm(
    const ush* __restrict__ A, const ush* __restrict__ Bt, ush* __restrict__ C,
    int M, int K, int N)
{
    const int n0 = blockIdx.x * 64, m0 = blockIdx.y * 64;
    const int tid = threadIdx.x, w = tid >> 6, l = tid & 63;
    __shared__ uint4 As4[512], Bs4[512];   // 8KB each, rows of 128B, swizzled
    char* As = (char*)As4;
    char* Bs = (char*)Bs4;
    f4v acc[4] = {};

    for (int kt = 0; kt < K; kt += 64) {
        __syncthreads();
        #pragma unroll
        for (int j = 0; j < 2; ++j) {
            int idx = tid + j * 256;            // 0..511
            int r = idx >> 3, cc = idx & 7;     // row, 16B chunk
            uint4 av = *(const uint4*)&A[(size_t)(m0 + r) * K + kt + cc * 8];
            uint4 bv = *(const uint4*)&Bt[(size_t)(n0 + r) * K + kt + cc * 8];
            int so = (cc * 16) ^ ((r & 7) << 4);
            *(uint4*)(As + r * 128 + so) = av;
            *(uint4*)(Bs + r * 128 + so) = bv;
        }
        __syncthreads();
        #pragma unroll
        for (int ks = 0; ks < 2; ++ks) {
            const int ko = ks * 64 + (l >> 4) * 16;        // byte offset of this lane's 8 bf16
            const int ra = w * 16 + (l & 15);
            s8v a = *(s8v*)(As + ra * 128 + (ko ^ ((ra & 7) << 4)));
            #pragma unroll
            for (int ni = 0; ni < 4; ++ni) {
                const int rb = ni * 16 + (l & 15);
                s8v b = *(s8v*)(Bs + rb * 128 + (ko ^ ((rb & 7) << 4)));
                acc[ni] = __builtin_amdgcn_mfma_f32_16x16x32_bf16(a, b, acc[ni], 0, 0, 0);
            }
        }
    }
    const int row_base = m0 + w * 16 + (l >> 4) * 4;
    const int col_base = n0 + (l & 15);
    #pragma unroll
    for (int ni = 0; ni < 4; ++ni)
        #pragma unroll
        for (int r = 0; r < 4; ++r)
            C[(size_t)(row_base + r) * N + col_base + ni * 16] = f2bf(acc[ni][r]);
}

// -------- attention: per (b,h,v), q/k/v precomputed [.,256] slices at h*32 --------
template<int MASKED>
__global__ __launch_bounds__(256) void k_attn(
    const ush* __restrict__ Q, const ush* __restrict__ Kg, const ush* __restrict__ Vg,
    ush* __restrict__ O)
{
    const int v = blockIdx.x, h = blockIdx.y, b = blockIdx.z;
    const int tid = threadIdx.x;
    __shared__ float qs[NT * ND];               // 16KB (pre-scaled)
    __shared__ float ks[NT * 33], vs[NT * 33];  // 16.9KB each (pad -> conflict-free)
    __shared__ float plds[4][NT];               // per-wave p row

    const size_t base = ((size_t)b * NT * NV + v) * NC + h * ND;
    for (int i = tid; i < NT * ND / 8; i += 256) {
        int t = i >> 2, d8 = (i & 3) * 8;
        float tmp[8];
        unpack8(*(const uint4*)&Q[base + (size_t)t * NV * NC + d8], tmp);
        #pragma unroll
        for (int j = 0; j < 8; ++j) qs[t * ND + d8 + j] = tmp[j] * QSCALE;
        unpack8(*(const uint4*)&Kg[base + (size_t)t * NV * NC + d8], &ks[t * 33 + d8]);
        unpack8(*(const uint4*)&Vg[base + (size_t)t * NV * NC + d8], &vs[t * 33 + d8]);
    }
    __syncthreads();
    const int w = tid >> 6, lane = tid & 63;
    const int half = lane >> 5, dd = lane & 31;
    ush* og = (ush*)O + base;
    for (int i = 0; i < 32; ++i) {
        const int t = w + 4 * i;
        float a0 = 0.f, a1 = 0.f;
        #pragma unroll 8
        for (int c = 0; c < ND; ++c) {
            float qv = qs[t * ND + c];
            a0 += qv * ks[lane * 33 + c];
            a1 += qv * ks[(lane + 64) * 33 + c];
        }
        if (MASKED) { if (lane > t) a0 = -1e30f; if (lane + 64 > t) a1 = -1e30f; }
        float mx = fmaxf(a0, a1);
        #pragma unroll
        for (int o = 32; o; o >>= 1) mx = fmaxf(mx, __shfl_xor(mx, o));
        float e0 = __expf(a0 - mx), e1 = __expf(a1 - mx);
        if (MASKED) { e0 = (lane <= t) ? e0 : 0.f; e1 = (lane + 64 <= t) ? e1 : 0.f; }
        float sm = e0 + e1;
        #pragma unroll
        for (int o = 32; o; o >>= 1) sm += __shfl_xor(sm, o);
        plds[w][lane] = e0;
        plds[w][lane + 64] = e1;
        asm volatile("s_waitcnt lgkmcnt(0)" ::: "memory");
        __builtin_amdgcn_sched_barrier(0);      // rule #18: keep reads after the wait
        float acc = 0.f;
        const int sb = half * 64;
        #pragma unroll 8
        for (int j = 0; j < 64; ++j)
            acc += plds[w][sb + j] * vs[(sb + j) * 33 + dd];
        acc += __shfl_xor(acc, 32);
        if (lane < 32) og[(size_t)t * NV * NC + dd] = f2bf(acc / sm);
    }
}

// ---------------- row LayerNorm (unbiased std), in place, 1 wave = 1 row ----------------
__global__ __launch_bounds__(256) void k_ln(
    ush* __restrict__ buf, const ush* __restrict__ g, const ush* __restrict__ bb)
{
    const int row = blockIdx.x * 4 + (threadIdx.x >> 6);
    const int lane = threadIdx.x & 63;
    ush* p = buf + (size_t)row * NC + lane * 4;
    uint2 u = *(uint2*)p;
    float x0 = bf2f((ush)(u.x & 0xffff)), x1 = bf2f((ush)(u.x >> 16));
    float x2 = bf2f((ush)(u.y & 0xffff)), x3 = bf2f((ush)(u.y >> 16));
    float s = x0 + x1 + x2 + x3;
    float q = x0 * x0 + x1 * x1 + x2 * x2 + x3 * x3;
    #pragma unroll
    for (int o = 32; o; o >>= 1) { s += __shfl_xor(s, o); q += __shfl_xor(q, o); }
    float mean = s * (1.f / 256.f);
    float var = fmaxf((q - 256.f * mean * mean) * (1.f / 255.f), 0.f);
    float inv = 1.f / (sqrtf(var) + LN_EPS);
    float o0 = bf2f(g[lane * 4 + 0]) * (x0 - mean) * inv + bf2f(bb[lane * 4 + 0]);
    float o1 = bf2f(g[lane * 4 + 1]) * (x1 - mean) * inv + bf2f(bb[lane * 4 + 1]);
    float o2 = bf2f(g[lane * 4 + 2]) * (x2 - mean) * inv + bf2f(bb[lane * 4 + 2]);
    float o3 = bf2f(g[lane * 4 + 3]) * (x3 - mean) * inv + bf2f(bb[lane * 4 + 3]);
    uint32 lo = (uint32)f2bf(o0) | ((uint32)f2bf(o1) << 16);
    uint32 hi = (uint32)f2bf(o2) | ((uint32)f2bf(o3) << 16);
    *(uint2*)p = make_uint2(lo, hi);
}

// ---------------- stage 3: Wg expansion + GCN contraction + LayerNorm, f32 output ----------------
__global__ __launch_bounds__(256) void k_stage3(
    const ush* __restrict__ h2, const ush* __restrict__ Wg, const ush* __restrict__ bg,
    const ush* __restrict__ A, const ush* __restrict__ g3, const ush* __restrict__ b3,
    float* __restrict__ outp)
{
    const int t = blockIdx.x, b = blockIdx.y;
    const int tid = threadIdx.x;
    __shared__ char smem[61952];
    ush* hs = (ush*)smem;                  // [25*256] bf16 (phase A)
    ush* wgs = (ush*)(smem + 12800);       // [32*768] bf16 (phase A)
    float* As = (float*)smem;              // [1875] f32 (phase B, reuses hs)
    float* h3s = (float*)(smem + 7504);    // [25*256] f32 (phase B/C, reuses wgs)

    const ush* hg = h2 + ((size_t)(b * NT + t)) * NV * NC;
    for (int i = tid; i < NV * NC / 8; i += 256)
        *(uint4*)&hs[i * 8] = *(const uint4*)&hg[i * 8];

    float acc[75];
    #pragma unroll
    for (int j = 0; j < 75; ++j) acc[j] = bf2f(bg[(j % 3) * 256 + tid]);

    for (int ci0 = 0; ci0 < 256; ci0 += 32) {
        __syncthreads();
        for (int i = tid; i < 32 * 768 / 8; i += 256) {
            int r = i / 96, c8 = (i % 96) * 8;
            *(uint4*)&wgs[r * 768 + c8] = *(const uint4*)&Wg[(size_t)(ci0 + r) * NKC + c8];
        }
        __syncthreads();
        for (int ci = 0; ci < 32; ++ci) {
            float w0 = bf2f(wgs[ci * 768 + tid]);
            float w1 = bf2f(wgs[ci * 768 + 256 + tid]);
            float w2v = bf2f(wgs[ci * 768 + 512 + tid]);
            #pragma unroll
            for (int vv = 0; vv < 25; ++vv) {
                float xv = bf2f(hs[vv * 256 + ci0 + ci]);
                acc[vv * 3 + 0] += xv * w0;
                acc[vv * 3 + 1] += xv * w1;
                acc[vv * 3 + 2] += xv * w2v;
            }
        }
    }
    __syncthreads();
    for (int i = tid; i < NK * NV * NV; i += 256) As[i] = bf2f(A[i]);
    __syncthreads();
    for (int w = 0; w < NV; ++w) {
        float a = 0.f;
        #pragma unroll
        for (int k = 0; k < NK; ++k)
            #pragma unroll
            for (int vv = 0; vv < NV; ++vv)
                a += As[k * 625 + vv * 25 + w] * acc[vv * 3 + k];
        h3s[w * 256 + tid] = a;
    }
    __syncthreads();
    {
        const int wv = tid >> 6, lane = tid & 63;
        for (int w = wv; w < NV; w += 4) {
            float x0 = h3s[w * 256 + lane * 4 + 0];
            float x1 = h3s[w * 256 + lane * 4 + 1];
            float x2 = h3s[w * 256 + lane * 4 + 2];
            float x3 = h3s[w * 256 + lane * 4 + 3];
            float s = x0 + x1 + x2 + x3;
            float q = x0 * x0 + x1 * x1 + x2 * x2 + x3 * x3;
            #pragma unroll
            for (int o = 32; o; o >>= 1) { s += __shfl_xor(s, o); q += __shfl_xor(q, o); }
            float mean = s * (1.f / 256.f);
            float var = fmaxf((q - 256.f * mean * mean) * (1.f / 255.f), 0.f);
            float inv = 1.f / (sqrtf(var) + LN_EPS);
            float o0 = bf2f(g3[lane * 4 + 0]) * (x0 - mean) * inv + bf2f(b3[lane * 4 + 0]);
            float o1 = bf2f(g3[lane * 4 + 1]) * (x1 - mean) * inv + bf2f(b3[lane * 4 + 1]);
            float o2 = bf2f(g3[lane * 4 + 2]) * (x2 - mean) * inv + bf2f(b3[lane * 4 + 2]);
            float o3 = bf2f(g3[lane * 4 + 3]) * (x3 - mean) * inv + bf2f(b3[lane * 4 + 3]);
            float* op = outp + (((size_t)(b * NT + t)) * NV + w) * NC + lane * 4;
            *(float4*)op = make_float4(o0, o1, o2, o3);
        }
    }
}

extern "C" void kernel_launch(void* const* d_in, const int* in_sizes, int n_in,
                              void* d_out, int out_size, void* d_ws, size_t ws_size,
                              hipStream_t stream)
{
    const size_t NTOK = (size_t)NB * NT * NV;         // 51200
    const size_t BUFE = NTOK * NC;                    // 13,107,200 elems
    char* ws = (char*)d_ws;
    int* flag = (int*)ws;
    ush* buf0 = (ush*)(ws + 256);
    ush* buf1 = buf0 + BUFE;
    ush* buf2 = buf1 + BUFE;
    ush* buf3 = buf2 + BUFE;
    ush* conv = buf3 + BUFE;

    // conversion plan: {src_idx, elems, transposeK (0 = plain copy)}
    struct CV { int idx; int n; int K; };
    const CV plan[13] = {
        {0, NB*NT*NV*NCIN, 0},   // x
        {1, NB*NTM*NV*NCM, 0},   // m
        {2, NK*NV*NV, 0},        // A
        {14, NC*NKC, 0},         // Wg
        {15, NKC, 0},            // bg
        {7, NC, 0}, {8, NC, 0}, {12, NC, 0}, {13, NC, 0}, {16, NC, 0}, {17, NC, 0},
        {4, NCIN*NC, NCIN},      // Wq1 -> [256][64]
        {5, NCIN*NC, NCIN},      // Wk1
    };
    // (remaining transposes issued below to keep pointer bookkeeping simple)

    k_detect<<<1, 256, 0, stream>>>((const uint32*)d_in[0], flag);

    ush* p = conv;
    const ush* cp[18] = {};
    for (int i = 0; i < 13; ++i) {
        const CV& c = plan[i];
        if (c.K == 0) {
            int blocks = (c.n + 255) / 256; if (blocks > 4096) blocks = 4096;
            k_convert<<<blocks, 256, 0, stream>>>(d_in[c.idx], p, c.n, flag);
        } else {
            k_convT<<<(c.n + 255) / 256, 256, 0, stream>>>(d_in[c.idx], p, c.K, NC, flag);
        }
        cp[c.idx] = p;
        p += (size_t)((c.n + 7) & ~7);
    }
    // Wv1, Wq2, Wk2, Wv2 transposed
    const int tidx[4] = {6, 9, 10, 11};
    const int tK[4] = {NCIN, NC, NCM, NCM};
    for (int i = 0; i < 4; ++i) {
        int n = tK[i] * NC;
        k_convT<<<(n + 255) / 256, 256, 0, stream>>>(d_in[tidx[i]], p, tK[i], NC, flag);
        cp[tidx[i]] = p;
        p += (size_t)((n + 7) & ~7);
    }

    const int M = (int)NTOK;
    // stage 1 projections: q1,k1,v1 = x @ W*1   (K=64)
    k_gemm<<<dim3(4, M / 64), 256, 0, stream>>>(cp[0], cp[4], buf0, M, NCIN, NC);
    k_gemm<<<dim3(4, M / 64), 256, 0, stream>>>(cp[0], cp[5], buf1, M, NCIN, NC);
    k_gemm<<<dim3(4, M / 64), 256, 0, stream>>>(cp[0], cp[6], buf2, M, NCIN, NC);
    // stage 1 attention (causal) -> h1 = buf3
    k_attn<1><<<dim3(NV, NH, NB), 256, 0, stream>>>(buf0, buf1, buf2, buf3);
    k_ln<<<M / 4, 256, 0, stream>>>(buf3, cp[7], cp[8]);
    // stage 2 projections: q2 = h1 @ Wq2 ; k2,v2 = m @ W*2   (K=256)
    k_gemm<<<dim3(4, M / 64), 256, 0, stream>>>(buf3, cp[9], buf0, M, NC, NC);
    k_gemm<<<dim3(4, M / 64), 256, 0, stream>>>(cp[1], cp[10], buf1, M, NCM, NC);
    k_gemm<<<dim3(4, M / 64), 256, 0, stream>>>(cp[1], cp[11], buf2, M, NCM, NC);
    // stage 2 attention (unmasked) -> h2 = buf3
    k_attn<0><<<dim3(NV, NH, NB), 256, 0, stream>>>(buf0, buf1, buf2, buf3);
    k_ln<<<M / 4, 256, 0, stream>>>(buf3, cp[12], cp[13]);
    // stage 3
    k_stage3<<<dim3(NT, NB), 256, 0, stream>>>(buf3, cp[14], cp[15], cp[2], cp[16], cp[17],
                                               (float*)d_out);
}

// Round 5
// 946.608 us; speedup vs baseline: 3.0358x; 1.4453x over previous
//
#include <hip/hip_runtime.h>
#include <hip/hip_bf16.h>

typedef unsigned short ush;
typedef unsigned int uint32;
typedef __attribute__((ext_vector_type(8))) short s8v;   // 8 bf16 (4 VGPRs)
typedef __attribute__((ext_vector_type(4))) float f4v;   // MFMA accumulator

#define NB 16
#define NT 128
#define NTM 128
#define NV 25
#define NCIN 64
#define NCM 256
#define NH 8
#define ND 32
#define NC 256
#define NK 3
#define NKC 768
#define LN_EPS 1e-6f
#define QSCALE 0.17677669529663687f

__device__ __forceinline__ float bf2f(ush u) {
    union { uint32 i; float f; } x; x.i = ((uint32)u) << 16; return x.f;
}
__device__ __forceinline__ ush f2bf(float f) {
    union { float f; uint32 i; } x; x.f = f;
    uint32 r = x.i + 0x7FFFu + ((x.i >> 16) & 1u);
    return (ush)(r >> 16);
}
__device__ __forceinline__ void unpack8(uint4 u, float* dst) {
    dst[0] = bf2f((ush)(u.x & 0xffff)); dst[1] = bf2f((ush)(u.x >> 16));
    dst[2] = bf2f((ush)(u.y & 0xffff)); dst[3] = bf2f((ush)(u.y >> 16));
    dst[4] = bf2f((ush)(u.z & 0xffff)); dst[5] = bf2f((ush)(u.z >> 16));
    dst[6] = bf2f((ush)(u.w & 0xffff)); dst[7] = bf2f((ush)(u.w >> 16));
}

// -------- dtype detector (f32 vs bf16 device buffers) --------
__global__ __launch_bounds__(256) void k_detect(const uint32* __restrict__ xw,
                                               int* __restrict__ flag)
{
    __shared__ int cnt;
    if (threadIdx.x == 0) cnt = 0;
    __syncthreads();
    int c = 0;
    for (int i = 0; i < 4; ++i) {
        uint32 u = xw[threadIdx.x + 256 * i];
        uint32 e = (u >> 7) & 0xFF;
        c += (e >= 100 && e <= 135) ? 1 : 0;
    }
    atomicAdd(&cnt, c);
    __syncthreads();
    if (threadIdx.x == 0) *flag = (cnt > 700) ? 1 : 0;   // 1 = bf16, 0 = f32
}

__global__ __launch_bounds__(256) void k_convert(const void* __restrict__ src,
                                                 ush* __restrict__ dst, int n,
                                                 const int* __restrict__ flag)
{
    const bool isbf = (*flag != 0);
    for (int i = blockIdx.x * 256 + threadIdx.x; i < n; i += gridDim.x * 256) {
        dst[i] = isbf ? ((const ush*)src)[i] : f2bf(((const float*)src)[i]);
    }
}

// src (f32 or bf16) -> dst f32
__global__ __launch_bounds__(256) void k_convF(const void* __restrict__ src,
                                               float* __restrict__ dst, int n,
                                               const int* __restrict__ flag)
{
    const bool isbf = (*flag != 0);
    int i = blockIdx.x * 256 + threadIdx.x;
    if (i < n) dst[i] = isbf ? bf2f(((const ush*)src)[i]) : ((const float*)src)[i];
}

// transpose-convert: src [K,N] (f32 or bf16) -> dst [N,K] bf16
__global__ __launch_bounds__(256) void k_convT(const void* __restrict__ src,
                                               ush* __restrict__ dst, int K, int N,
                                               const int* __restrict__ flag)
{
    const bool isbf = (*flag != 0);
    int idx = blockIdx.x * 256 + threadIdx.x;
    if (idx >= K * N) return;
    int n = idx / K, k = idx - n * K;
    dst[idx] = isbf ? ((const ush*)src)[k * N + n] : f2bf(((const float*)src)[k * N + n]);
}

// -------- generic MFMA GEMM: C[M, ldC slice] = A[M,K] @ Bt[64*bx..][K]^T --------
// BM=128, BN=64, BK=64, 4 waves; XOR-swizzled 128B LDS rows; 16x16x32 bf16.
__global__ __launch_bounds__(256) void k_gemm(
    const ush* __restrict__ A, const ush* __restrict__ Bt, ush* __restrict__ C,
    int M, int K, int ldC)
{
    const int n0 = blockIdx.x * 64, m0 = blockIdx.y * 128;
    const int tid = threadIdx.x, w = tid >> 6, l = tid & 63;
    __shared__ uint4 As4[1024], Bs4[512];   // 16KB + 8KB
    char* As = (char*)As4;
    char* Bs = (char*)Bs4;
    f4v acc[2][4] = {};

    for (int kt = 0; kt < K; kt += 64) {
        __syncthreads();
        #pragma unroll
        for (int j = 0; j < 4; ++j) {
            int idx = tid + j * 256;
            int r = idx >> 3, cc = idx & 7;
            uint4 av = *(const uint4*)&A[(size_t)(m0 + r) * K + kt + cc * 8];
            *(uint4*)(As + r * 128 + ((cc * 16) ^ ((r & 7) << 4))) = av;
        }
        #pragma unroll
        for (int j = 0; j < 2; ++j) {
            int idx = tid + j * 256;
            int r = idx >> 3, cc = idx & 7;
            uint4 bv = *(const uint4*)&Bt[(size_t)(n0 + r) * K + kt + cc * 8];
            *(uint4*)(Bs + r * 128 + ((cc * 16) ^ ((r & 7) << 4))) = bv;
        }
        __syncthreads();
        #pragma unroll
        for (int ks = 0; ks < 2; ++ks) {
            const int ko = ks * 64 + (l >> 4) * 16;
            const int ra0 = w * 32 + (l & 15), ra1 = ra0 + 16;
            s8v a0 = *(s8v*)(As + ra0 * 128 + (ko ^ ((ra0 & 7) << 4)));
            s8v a1 = *(s8v*)(As + ra1 * 128 + (ko ^ ((ra1 & 7) << 4)));
            #pragma unroll
            for (int ni = 0; ni < 4; ++ni) {
                const int rb = ni * 16 + (l & 15);
                s8v b = *(s8v*)(Bs + rb * 128 + (ko ^ ((rb & 7) << 4)));
                acc[0][ni] = __builtin_amdgcn_mfma_f32_16x16x32_bf16(a0, b, acc[0][ni], 0, 0, 0);
                acc[1][ni] = __builtin_amdgcn_mfma_f32_16x16x32_bf16(a1, b, acc[1][ni], 0, 0, 0);
            }
        }
    }
    const int col = n0 + (l & 15);
    #pragma unroll
    for (int mi = 0; mi < 2; ++mi) {
        const int row_base = m0 + w * 32 + mi * 16 + (l >> 4) * 4;
        #pragma unroll
        for (int ni = 0; ni < 4; ++ni)
            #pragma unroll
            for (int r = 0; r < 4; ++r)
                C[(size_t)(row_base + r) * ldC + col + ni * 16] = f2bf(acc[mi][ni][r]);
    }
}

// -------- attention: per (b,h,v); q/k/v packed in one [M,768] buffer --------
template<int MASKED>
__global__ __launch_bounds__(256) void k_attn(
    const ush* __restrict__ QKV, ush* __restrict__ O)
{
    const int v = blockIdx.x, h = blockIdx.y, b = blockIdx.z;
    const int tid = threadIdx.x;
    __shared__ float qs[NT * ND];               // 16KB (pre-scaled)
    __shared__ float ks[NT * 33], vs[NT * 33];  // padded -> conflict-free
    __shared__ float plds[4][NT];

    const size_t qb = ((size_t)b * NT * NV + v) * 768 + h * ND;
    for (int i = tid; i < NT * ND / 8; i += 256) {
        int t = i >> 2, d8 = (i & 3) * 8;
        size_t ro = qb + (size_t)t * NV * 768 + d8;
        float tmp[8];
        unpack8(*(const uint4*)&QKV[ro], tmp);
        #pragma unroll
        for (int j = 0; j < 8; ++j) qs[t * ND + d8 + j] = tmp[j] * QSCALE;
        unpack8(*(const uint4*)&QKV[ro + 256], &ks[t * 33 + d8]);
        unpack8(*(const uint4*)&QKV[ro + 512], &vs[t * 33 + d8]);
    }
    __syncthreads();
    const int w = tid >> 6, lane = tid & 63;
    const int half = lane >> 5, dd = lane & 31;
    ush* og = O + ((size_t)b * NT * NV + v) * NC + h * ND;
    for (int i = 0; i < 32; ++i) {
        const int t = w + 4 * i;
        float a0 = 0.f, a1 = 0.f;
        #pragma unroll 8
        for (int c = 0; c < ND; ++c) {
            float qv = qs[t * ND + c];
            a0 += qv * ks[lane * 33 + c];
            a1 += qv * ks[(lane + 64) * 33 + c];
        }
        if (MASKED) { if (lane > t) a0 = -1e30f; if (lane + 64 > t) a1 = -1e30f; }
        float mx = fmaxf(a0, a1);
        #pragma unroll
        for (int o = 32; o; o >>= 1) mx = fmaxf(mx, __shfl_xor(mx, o));
        float e0 = __expf(a0 - mx), e1 = __expf(a1 - mx);
        if (MASKED) { e0 = (lane <= t) ? e0 : 0.f; e1 = (lane + 64 <= t) ? e1 : 0.f; }
        float sm = e0 + e1;
        #pragma unroll
        for (int o = 32; o; o >>= 1) sm += __shfl_xor(sm, o);
        plds[w][lane] = e0;
        plds[w][lane + 64] = e1;
        asm volatile("s_waitcnt lgkmcnt(0)" ::: "memory");
        __builtin_amdgcn_sched_barrier(0);
        float acc = 0.f;
        const int sb = half * 64;
        #pragma unroll 8
        for (int j = 0; j < 64; ++j)
            acc += plds[w][sb + j] * vs[(sb + j) * 33 + dd];
        acc += __shfl_xor(acc, 32);
        if (lane < 32) og[(size_t)t * NV * NC + dd] = f2bf(acc / sm);
    }
}

// ---------------- row LayerNorm (unbiased std), in place, 1 wave = 1 row ----------------
__global__ __launch_bounds__(256) void k_ln(
    ush* __restrict__ buf, const ush* __restrict__ g, const ush* __restrict__ bb)
{
    const int row = blockIdx.x * 4 + (threadIdx.x >> 6);
    const int lane = threadIdx.x & 63;
    ush* p = buf + (size_t)row * NC + lane * 4;
    uint2 u = *(uint2*)p;
    float x0 = bf2f((ush)(u.x & 0xffff)), x1 = bf2f((ush)(u.x >> 16));
    float x2 = bf2f((ush)(u.y & 0xffff)), x3 = bf2f((ush)(u.y >> 16));
    float s = x0 + x1 + x2 + x3;
    float q = x0 * x0 + x1 * x1 + x2 * x2 + x3 * x3;
    #pragma unroll
    for (int o = 32; o; o >>= 1) { s += __shfl_xor(s, o); q += __shfl_xor(q, o); }
    float mean = s * (1.f / 256.f);
    float var = fmaxf((q - 256.f * mean * mean) * (1.f / 255.f), 0.f);
    float inv = 1.f / (sqrtf(var) + LN_EPS);
    float o0 = bf2f(g[lane * 4 + 0]) * (x0 - mean) * inv + bf2f(bb[lane * 4 + 0]);
    float o1 = bf2f(g[lane * 4 + 1]) * (x1 - mean) * inv + bf2f(bb[lane * 4 + 1]);
    float o2 = bf2f(g[lane * 4 + 2]) * (x2 - mean) * inv + bf2f(bb[lane * 4 + 2]);
    float o3 = bf2f(g[lane * 4 + 3]) * (x3 - mean) * inv + bf2f(bb[lane * 4 + 3]);
    uint32 lo = (uint32)f2bf(o0) | ((uint32)f2bf(o1) << 16);
    uint32 hi = (uint32)f2bf(o2) | ((uint32)f2bf(o3) << 16);
    *(uint2*)p = make_uint2(lo, hi);
}

// -------- GCN contraction + bias + LayerNorm; A coefficients via scalar loads --------
__global__ __launch_bounds__(256) void k_gcn(
    const ush* __restrict__ xw, const float* __restrict__ Af,
    const ush* __restrict__ bg, const ush* __restrict__ g3, const ush* __restrict__ b3,
    float* __restrict__ outp)
{
    const int t = blockIdx.x, b = blockIdx.y;
    const int tid = threadIdx.x;
    __shared__ float cs[80];
    __shared__ float h3s[NV * NC];   // 25.6KB

    if (tid < 75) {
        int k = tid / 25, w = tid - k * 25;
        float s = 0.f;
        #pragma unroll
        for (int v = 0; v < NV; ++v) s += Af[k * 625 + v * 25 + w];
        cs[tid] = s;
    }
    const ush* xr = xw + ((size_t)(b * NT + t)) * NV * NKC;
    float xv[75];
    #pragma unroll
    for (int v = 0; v < NV; ++v)
        #pragma unroll
        for (int k = 0; k < NK; ++k)
            xv[v * 3 + k] = bf2f(xr[v * NKC + k * NC + tid]);
    float bgv[3];
    #pragma unroll
    for (int k = 0; k < NK; ++k) bgv[k] = bf2f(bg[k * NC + tid]);
    __syncthreads();
    for (int w = 0; w < NV; ++w) {
        float a = bgv[0] * cs[w] + bgv[1] * cs[25 + w] + bgv[2] * cs[50 + w];
        #pragma unroll
        for (int k = 0; k < NK; ++k)
            #pragma unroll
            for (int v = 0; v < NV; ++v)
                a += Af[k * 625 + v * 25 + w] * xv[v * 3 + k];   // uniform -> s_load
        h3s[w * NC + tid] = a;
    }
    __syncthreads();
    {
        const int wv = tid >> 6, lane = tid & 63;
        for (int w = wv; w < NV; w += 4) {
            float x0 = h3s[w * NC + lane * 4 + 0];
            float x1 = h3s[w * NC + lane * 4 + 1];
            float x2 = h3s[w * NC + lane * 4 + 2];
            float x3 = h3s[w * NC + lane * 4 + 3];
            float s = x0 + x1 + x2 + x3;
            float q = x0 * x0 + x1 * x1 + x2 * x2 + x3 * x3;
            #pragma unroll
            for (int o = 32; o; o >>= 1) { s += __shfl_xor(s, o); q += __shfl_xor(q, o); }
            float mean = s * (1.f / 256.f);
            float var = fmaxf((q - 256.f * mean * mean) * (1.f / 255.f), 0.f);
            float inv = 1.f / (sqrtf(var) + LN_EPS);
            float o0 = bf2f(g3[lane * 4 + 0]) * (x0 - mean) * inv + bf2f(b3[lane * 4 + 0]);
            float o1 = bf2f(g3[lane * 4 + 1]) * (x1 - mean) * inv + bf2f(b3[lane * 4 + 1]);
            float o2 = bf2f(g3[lane * 4 + 2]) * (x2 - mean) * inv + bf2f(b3[lane * 4 + 2]);
            float o3 = bf2f(g3[lane * 4 + 3]) * (x3 - mean) * inv + bf2f(b3[lane * 4 + 3]);
            float* op = outp + (((size_t)(b * NT + t)) * NV + w) * NC + lane * 4;
            *(float4*)op = make_float4(o0, o1, o2, o3);
        }
    }
}

extern "C" void kernel_launch(void* const* d_in, const int* in_sizes, int n_in,
                              void* d_out, int out_size, void* d_ws, size_t ws_size,
                              hipStream_t stream)
{
    const size_t NTOK = (size_t)NB * NT * NV;   // 51200
    char* ws = (char*)d_ws;
    int* flag = (int*)ws;
    float* Af = (float*)(ws + 256);             // A as f32, 7.5KB
    ush* bufA = (ush*)(ws + 8192);              // [M,768]  78.6MB
    ush* bufB = bufA + NTOK * NKC;              // [M,256]  26.2MB
    ush* conv = bufB + NTOK * NC;

    k_detect<<<1, 256, 0, stream>>>((const uint32*)d_in[0], flag);
    k_convF<<<8, 256, 0, stream>>>(d_in[2], Af, NK * NV * NV, flag);

    ush* p = conv;
    const ush* cp[18] = {};
    // plain copies: x, m, bg, g1,b1,g2,b2,g3,b3
    const int pidx[9] = {0, 1, 15, 7, 8, 12, 13, 16, 17};
    const int pn[9]   = {NB*NT*NV*NCIN, NB*NTM*NV*NCM, NKC, NC, NC, NC, NC, NC, NC};
    for (int i = 0; i < 9; ++i) {
        int n = pn[i];
        int blocks = (n + 255) / 256; if (blocks > 4096) blocks = 4096;
        k_convert<<<blocks, 256, 0, stream>>>(d_in[pidx[i]], p, n, flag);
        cp[pidx[i]] = p;
        p += (size_t)((n + 7) & ~7);
    }
    // stacked transposed weights
    ush* w1t = p;   // [768][64]: q | k | v
    k_convT<<<64, 256, 0, stream>>>(d_in[4], w1t,          NCIN, NC, flag);
    k_convT<<<64, 256, 0, stream>>>(d_in[5], w1t + 16384,  NCIN, NC, flag);
    k_convT<<<64, 256, 0, stream>>>(d_in[6], w1t + 32768,  NCIN, NC, flag);
    p += 49152;
    ush* wq2t = p;  // [256][256]
    k_convT<<<256, 256, 0, stream>>>(d_in[9], wq2t, NC, NC, flag);
    p += 65536;
    ush* wkv2t = p; // [512][256]: k | v
    k_convT<<<256, 256, 0, stream>>>(d_in[10], wkv2t,         NCM, NC, flag);
    k_convT<<<256, 256, 0, stream>>>(d_in[11], wkv2t + 65536, NCM, NC, flag);
    p += 131072;
    ush* wgt = p;   // [768][256]
    k_convT<<<768, 256, 0, stream>>>(d_in[14], wgt, NC, NKC, flag);
    p += 196608;

    const int M = (int)NTOK;
    // stage 1: qkv1 = x @ [Wq1|Wk1|Wv1]  -> bufA [M,768]
    k_gemm<<<dim3(12, M / 128), 256, 0, stream>>>(cp[0], w1t, bufA, M, NCIN, NKC);
    k_attn<1><<<dim3(NV, NH, NB), 256, 0, stream>>>(bufA, bufB);
    k_ln<<<M / 4, 256, 0, stream>>>(bufB, cp[7], cp[8]);
    // stage 2: q2 = h1 @ Wq2 (cols 0-255); kv2 = m @ [Wk2|Wv2] (cols 256-767)
    k_gemm<<<dim3(4, M / 128), 256, 0, stream>>>(bufB, wq2t, bufA, M, NC, NKC);
    k_gemm<<<dim3(8, M / 128), 256, 0, stream>>>(cp[1], wkv2t, bufA + 256, M, NCM, NKC);
    k_attn<0><<<dim3(NV, NH, NB), 256, 0, stream>>>(bufA, bufB);
    k_ln<<<M / 4, 256, 0, stream>>>(bufB, cp[12], cp[13]);
    // stage 3: xw = h2 @ Wg -> bufA [M,768]; then GCN+LN -> out
    k_gemm<<<dim3(12, M / 128), 256, 0, stream>>>(bufB, wgt, bufA, M, NC, NKC);
    k_gcn<<<dim3(NT, NB), 256, 0, stream>>>(bufA, Af, cp[15], cp[16], cp[17], (float*)d_out);
}

// Round 6
// 348.405 us; speedup vs baseline: 8.2482x; 2.7170x over previous
//
#include <hip/hip_runtime.h>
#include <hip/hip_bf16.h>

typedef unsigned short ush;
typedef unsigned int uint32;
typedef __attribute__((ext_vector_type(8))) short s8v;   // 8 bf16 (4 VGPRs)
typedef __attribute__((ext_vector_type(4))) float f4v;   // MFMA accumulator

#define NB 16
#define NT 128
#define NTM 128
#define NV 25
#define NCIN 64
#define NCM 256
#define NH 8
#define ND 32
#define NC 256
#define NK 3
#define NKC 768
#define LN_EPS 1e-6f
#define QSCALE 0.17677669529663687f

__device__ __forceinline__ float bf2f(ush u) {
    union { uint32 i; float f; } x; x.i = ((uint32)u) << 16; return x.f;
}
__device__ __forceinline__ ush f2bf(float f) {
    union { float f; uint32 i; } x; x.f = f;
    uint32 r = x.i + 0x7FFFu + ((x.i >> 16) & 1u);
    return (ush)(r >> 16);
}

// -------- dtype detector (f32 vs bf16 device buffers) --------
__global__ __launch_bounds__(256) void k_detect(const uint32* __restrict__ xw,
                                               int* __restrict__ flag)
{
    __shared__ int cnt;
    if (threadIdx.x == 0) cnt = 0;
    __syncthreads();
    int c = 0;
    for (int i = 0; i < 4; ++i) {
        uint32 u = xw[threadIdx.x + 256 * i];
        uint32 e = (u >> 7) & 0xFF;
        c += (e >= 100 && e <= 135) ? 1 : 0;
    }
    atomicAdd(&cnt, c);
    __syncthreads();
    if (threadIdx.x == 0) *flag = (cnt > 700) ? 1 : 0;   // 1 = bf16, 0 = f32
}

__global__ __launch_bounds__(256) void k_convert(const void* __restrict__ src,
                                                 ush* __restrict__ dst, int n,
                                                 const int* __restrict__ flag)
{
    const bool isbf = (*flag != 0);
    for (int i = blockIdx.x * 256 + threadIdx.x; i < n; i += gridDim.x * 256) {
        dst[i] = isbf ? ((const ush*)src)[i] : f2bf(((const float*)src)[i]);
    }
}

// src (f32 or bf16) -> dst f32
__global__ __launch_bounds__(256) void k_convF(const void* __restrict__ src,
                                               float* __restrict__ dst, int n,
                                               const int* __restrict__ flag)
{
    const bool isbf = (*flag != 0);
    int i = blockIdx.x * 256 + threadIdx.x;
    if (i < n) dst[i] = isbf ? bf2f(((const ush*)src)[i]) : ((const float*)src)[i];
}

// transpose-convert: src [K,N] (f32 or bf16) -> dst [N,K] bf16
__global__ __launch_bounds__(256) void k_convT(const void* __restrict__ src,
                                               ush* __restrict__ dst, int K, int N,
                                               const int* __restrict__ flag)
{
    const bool isbf = (*flag != 0);
    int idx = blockIdx.x * 256 + threadIdx.x;
    if (idx >= K * N) return;
    int n = idx / K, k = idx - n * K;
    dst[idx] = isbf ? ((const ush*)src)[k * N + n] : f2bf(((const float*)src)[k * N + n]);
}

// -------- generic MFMA GEMM: C[M, ldC slice] = A[M,K] @ Bt[64*bx..][K]^T --------
__global__ __launch_bounds__(256) void k_gemm(
    const ush* __restrict__ A, const ush* __restrict__ Bt, ush* __restrict__ C,
    int M, int K, int ldC)
{
    const int n0 = blockIdx.x * 64, m0 = blockIdx.y * 128;
    const int tid = threadIdx.x, w = tid >> 6, l = tid & 63;
    __shared__ uint4 As4[1024], Bs4[512];   // 16KB + 8KB
    char* As = (char*)As4;
    char* Bs = (char*)Bs4;
    f4v acc[2][4] = {};

    for (int kt = 0; kt < K; kt += 64) {
        __syncthreads();
        #pragma unroll
        for (int j = 0; j < 4; ++j) {
            int idx = tid + j * 256;
            int r = idx >> 3, cc = idx & 7;
            uint4 av = *(const uint4*)&A[(size_t)(m0 + r) * K + kt + cc * 8];
            *(uint4*)(As + r * 128 + ((cc * 16) ^ ((r & 7) << 4))) = av;
        }
        #pragma unroll
        for (int j = 0; j < 2; ++j) {
            int idx = tid + j * 256;
            int r = idx >> 3, cc = idx & 7;
            uint4 bv = *(const uint4*)&Bt[(size_t)(n0 + r) * K + kt + cc * 8];
            *(uint4*)(Bs + r * 128 + ((cc * 16) ^ ((r & 7) << 4))) = bv;
        }
        __syncthreads();
        #pragma unroll
        for (int ks = 0; ks < 2; ++ks) {
            const int ko = ks * 64 + (l >> 4) * 16;
            const int ra0 = w * 32 + (l & 15), ra1 = ra0 + 16;
            s8v a0 = *(s8v*)(As + ra0 * 128 + (ko ^ ((ra0 & 7) << 4)));
            s8v a1 = *(s8v*)(As + ra1 * 128 + (ko ^ ((ra1 & 7) << 4)));
            #pragma unroll
            for (int ni = 0; ni < 4; ++ni) {
                const int rb = ni * 16 + (l & 15);
                s8v b = *(s8v*)(Bs + rb * 128 + (ko ^ ((rb & 7) << 4)));
                acc[0][ni] = __builtin_amdgcn_mfma_f32_16x16x32_bf16(a0, b, acc[0][ni], 0, 0, 0);
                acc[1][ni] = __builtin_amdgcn_mfma_f32_16x16x32_bf16(a1, b, acc[1][ni], 0, 0, 0);
            }
        }
    }
    const int col = n0 + (l & 15);
    #pragma unroll
    for (int mi = 0; mi < 2; ++mi) {
        const int row_base = m0 + w * 32 + mi * 16 + (l >> 4) * 4;
        #pragma unroll
        for (int ni = 0; ni < 4; ++ni)
            #pragma unroll
            for (int r = 0; r < 4; ++r)
                C[(size_t)(row_base + r) * ldC + col + ni * 16] = f2bf(acc[mi][ni][r]);
    }
}

// -------- MFMA attention: 1 wave = 1 (b,h,v) head; zero LDS --------
// Swapped QK^T: ST[s][t] = mfma(Kfrag, Qfrag) -> softmax over s is lane-local.
// Verified layouts (m89): A: row=l&15, k=(l>>4)*8+j; B: col=l&15, same k;
//                         D: row=(l>>4)*4+r, col=l&15.
template<int MASKED>
__global__ __launch_bounds__(64) void k_attn_mfma(
    const ush* __restrict__ QKV, ush* __restrict__ O)
{
    const int v = blockIdx.x, h = blockIdx.y, b = blockIdx.z;
    const int l = threadIdx.x, g = l >> 4, c = l & 15;
    const size_t tokStride = (size_t)NV * NKC;
    const ush* base = QKV + ((size_t)b * NT * NV + v) * NKC;

    // K fragments (A-operand): kf[si]: row s = 16si + c, k = d = 8g..8g+7
    s8v kf[8];
    const int koff = 256 + h * ND + g * 8;
    #pragma unroll
    for (int si = 0; si < 8; ++si)
        kf[si] = *(const s8v*)(base + (size_t)(16 * si + c) * tokStride + koff);

    // V^T fragments (B-operand): vf[ks][ni]: col d = 16ni + c, k = s = 32ks+8g+j
    s8v vf[4][2];
    #pragma unroll
    for (int ks = 0; ks < 4; ++ks)
        #pragma unroll
        for (int ni = 0; ni < 2; ++ni) {
            const int voff = 512 + h * ND + 16 * ni + c;
            s8v tmp;
            #pragma unroll
            for (int j = 0; j < 8; ++j)
                tmp[j] = (short)base[(size_t)(32 * ks + 8 * g + j) * tokStride + voff];
            vf[ks][ni] = tmp;
        }

    ush* og = O + ((size_t)b * NT * NV + v) * NC + h * ND;
    const int qoff = h * ND + g * 8;
    const int ga = (g & 1) * 2;
    const int l1 = ga * 16 + c, l2 = l1 + 16;
    const bool hisel = (g >> 1) != 0;

    for (int t16 = 0; t16 < 8; ++t16) {
        // Q fragment: col t = 16*t16 + c
        s8v qf = *(const s8v*)(base + (size_t)(16 * t16 + c) * tokStride + qoff);
        // QK^T: st[si] = ST tile (s block si, t block t16)
        f4v st[8];
        #pragma unroll
        for (int si = 0; si < 8; ++si)
            st[si] = __builtin_amdgcn_mfma_f32_16x16x32_bf16(kf[si], qf,
                                                             (f4v){0.f, 0.f, 0.f, 0.f}, 0, 0, 0);
        const int t = 16 * t16 + c;   // this lane's column (query time)
        if (MASKED) {
            #pragma unroll
            for (int si = 0; si < 8; ++si)
                #pragma unroll
                for (int r = 0; r < 4; ++r)
                    if (16 * si + 4 * g + r > t) st[si][r] = -1e30f;
        }
        // softmax over s (in-register 32 + xor16/32), normalize, pack to bf16
        float mx = -1e30f;
        #pragma unroll
        for (int si = 0; si < 8; ++si)
            #pragma unroll
            for (int r = 0; r < 4; ++r) mx = fmaxf(mx, st[si][r]);
        mx = fmaxf(mx, __shfl_xor(mx, 16));
        mx = fmaxf(mx, __shfl_xor(mx, 32));
        float sm = 0.f;
        #pragma unroll
        for (int si = 0; si < 8; ++si)
            #pragma unroll
            for (int r = 0; r < 4; ++r) {
                float e = __expf((st[si][r] - mx) * QSCALE);
                st[si][r] = e;
                sm += e;
            }
        sm += __shfl_xor(sm, 16);
        sm += __shfl_xor(sm, 32);
        const float inv = 1.f / sm;
        uint32 u[8][2];   // u[si][p]: packed bf16 pairs (r0,r1),(r2,r3) = s_local 4g..4g+3
        #pragma unroll
        for (int si = 0; si < 8; ++si) {
            float e0 = st[si][0] * inv, e1 = st[si][1] * inv;
            float e2 = st[si][2] * inv, e3 = st[si][3] * inv;
            asm("v_cvt_pk_bf16_f32 %0, %1, %2" : "=v"(u[si][0]) : "v"(e0), "v"(e1));
            asm("v_cvt_pk_bf16_f32 %0, %1, %2" : "=v"(u[si][1]) : "v"(e2), "v"(e3));
        }
        // PV: assemble P A-fragments via shfl (k = s = 32ks + 8g + j)
        f4v o[2] = {};
        #pragma unroll
        for (int ks = 0; ks < 4; ++ks) {
            uint32 w0a = __shfl(u[2 * ks][0], l1),     w0b = __shfl(u[2 * ks][1], l1);
            uint32 w0c = __shfl(u[2 * ks][0], l2),     w0d = __shfl(u[2 * ks][1], l2);
            uint32 w1a = __shfl(u[2 * ks + 1][0], l1), w1b = __shfl(u[2 * ks + 1][1], l1);
            uint32 w1c = __shfl(u[2 * ks + 1][0], l2), w1d = __shfl(u[2 * ks + 1][1], l2);
            union { uint32 w[4]; s8v s; } pa;
            pa.w[0] = hisel ? w1a : w0a;
            pa.w[1] = hisel ? w1b : w0b;
            pa.w[2] = hisel ? w1c : w0c;
            pa.w[3] = hisel ? w1d : w0d;
            o[0] = __builtin_amdgcn_mfma_f32_16x16x32_bf16(pa.s, vf[ks][0], o[0], 0, 0, 0);
            o[1] = __builtin_amdgcn_mfma_f32_16x16x32_bf16(pa.s, vf[ks][1], o[1], 0, 0, 0);
        }
        // write O tile: row t = 16*t16 + 4g + r, col d = 16ni + c
        #pragma unroll
        for (int ni = 0; ni < 2; ++ni)
            #pragma unroll
            for (int r = 0; r < 4; ++r)
                og[(size_t)(16 * t16 + 4 * g + r) * (NV * NC) + 16 * ni + c] = f2bf(o[ni][r]);
    }
}

// ---------------- row LayerNorm (unbiased std), in place, 1 wave = 1 row ----------------
__global__ __launch_bounds__(256) void k_ln(
    ush* __restrict__ buf, const ush* __restrict__ g, const ush* __restrict__ bb)
{
    const int row = blockIdx.x * 4 + (threadIdx.x >> 6);
    const int lane = threadIdx.x & 63;
    ush* p = buf + (size_t)row * NC + lane * 4;
    uint2 u = *(uint2*)p;
    float x0 = bf2f((ush)(u.x & 0xffff)), x1 = bf2f((ush)(u.x >> 16));
    float x2 = bf2f((ush)(u.y & 0xffff)), x3 = bf2f((ush)(u.y >> 16));
    float s = x0 + x1 + x2 + x3;
    float q = x0 * x0 + x1 * x1 + x2 * x2 + x3 * x3;
    #pragma unroll
    for (int o = 32; o; o >>= 1) { s += __shfl_xor(s, o); q += __shfl_xor(q, o); }
    float mean = s * (1.f / 256.f);
    float var = fmaxf((q - 256.f * mean * mean) * (1.f / 255.f), 0.f);
    float inv = 1.f / (sqrtf(var) + LN_EPS);
    float o0 = bf2f(g[lane * 4 + 0]) * (x0 - mean) * inv + bf2f(bb[lane * 4 + 0]);
    float o1 = bf2f(g[lane * 4 + 1]) * (x1 - mean) * inv + bf2f(bb[lane * 4 + 1]);
    float o2 = bf2f(g[lane * 4 + 2]) * (x2 - mean) * inv + bf2f(bb[lane * 4 + 2]);
    float o3 = bf2f(g[lane * 4 + 3]) * (x3 - mean) * inv + bf2f(bb[lane * 4 + 3]);
    uint32 lo = (uint32)f2bf(o0) | ((uint32)f2bf(o1) << 16);
    uint32 hi = (uint32)f2bf(o2) | ((uint32)f2bf(o3) << 16);
    *(uint2*)p = make_uint2(lo, hi);
}

// -------- GCN contraction + bias + LayerNorm; A coefficients via scalar loads --------
__global__ __launch_bounds__(256) void k_gcn(
    const ush* __restrict__ xw, const float* __restrict__ Af,
    const ush* __restrict__ bg, const ush* __restrict__ g3, const ush* __restrict__ b3,
    float* __restrict__ outp)
{
    const int t = blockIdx.x, b = blockIdx.y;
    const int tid = threadIdx.x;
    __shared__ float cs[80];
    __shared__ float h3s[NV * NC];   // 25.6KB

    if (tid < 75) {
        int k = tid / 25, w = tid - k * 25;
        float s = 0.f;
        #pragma unroll
        for (int v = 0; v < NV; ++v) s += Af[k * 625 + v * 25 + w];
        cs[tid] = s;
    }
    const ush* xr = xw + ((size_t)(b * NT + t)) * NV * NKC;
    float xv[75];
    #pragma unroll
    for (int v = 0; v < NV; ++v)
        #pragma unroll
        for (int k = 0; k < NK; ++k)
            xv[v * 3 + k] = bf2f(xr[v * NKC + k * NC + tid]);
    float bgv[3];
    #pragma unroll
    for (int k = 0; k < NK; ++k) bgv[k] = bf2f(bg[k * NC + tid]);
    __syncthreads();
    for (int w = 0; w < NV; ++w) {
        float a = bgv[0] * cs[w] + bgv[1] * cs[25 + w] + bgv[2] * cs[50 + w];
        #pragma unroll
        for (int k = 0; k < NK; ++k)
            #pragma unroll
            for (int v = 0; v < NV; ++v)
                a += Af[k * 625 + v * 25 + w] * xv[v * 3 + k];   // uniform -> s_load
        h3s[w * NC + tid] = a;
    }
    __syncthreads();
    {
        const int wv = tid >> 6, lane = tid & 63;
        for (int w = wv; w < NV; w += 4) {
            float x0 = h3s[w * NC + lane * 4 + 0];
            float x1 = h3s[w * NC + lane * 4 + 1];
            float x2 = h3s[w * NC + lane * 4 + 2];
            float x3 = h3s[w * NC + lane * 4 + 3];
            float s = x0 + x1 + x2 + x3;
            float q = x0 * x0 + x1 * x1 + x2 * x2 + x3 * x3;
            #pragma unroll
            for (int o = 32; o; o >>= 1) { s += __shfl_xor(s, o); q += __shfl_xor(q, o); }
            float mean = s * (1.f / 256.f);
            float var = fmaxf((q - 256.f * mean * mean) * (1.f / 255.f), 0.f);
            float inv = 1.f / (sqrtf(var) + LN_EPS);
            float o0 = bf2f(g3[lane * 4 + 0]) * (x0 - mean) * inv + bf2f(b3[lane * 4 + 0]);
            float o1 = bf2f(g3[lane * 4 + 1]) * (x1 - mean) * inv + bf2f(b3[lane * 4 + 1]);
            float o2 = bf2f(g3[lane * 4 + 2]) * (x2 - mean) * inv + bf2f(b3[lane * 4 + 2]);
            float o3 = bf2f(g3[lane * 4 + 3]) * (x3 - mean) * inv + bf2f(b3[lane * 4 + 3]);
            float* op = outp + (((size_t)(b * NT + t)) * NV + w) * NC + lane * 4;
            *(float4*)op = make_float4(o0, o1, o2, o3);
        }
    }
}

extern "C" void kernel_launch(void* const* d_in, const int* in_sizes, int n_in,
                              void* d_out, int out_size, void* d_ws, size_t ws_size,
                              hipStream_t stream)
{
    const size_t NTOK = (size_t)NB * NT * NV;   // 51200
    char* ws = (char*)d_ws;
    int* flag = (int*)ws;
    float* Af = (float*)(ws + 256);             // A as f32, 7.5KB
    ush* bufA = (ush*)(ws + 8192);              // [M,768]  78.6MB
    ush* bufB = bufA + NTOK * NKC;              // [M,256]  26.2MB
    ush* conv = bufB + NTOK * NC;

    k_detect<<<1, 256, 0, stream>>>((const uint32*)d_in[0], flag);
    k_convF<<<8, 256, 0, stream>>>(d_in[2], Af, NK * NV * NV, flag);

    ush* p = conv;
    const ush* cp[18] = {};
    const int pidx[9] = {0, 1, 15, 7, 8, 12, 13, 16, 17};
    const int pn[9]   = {NB*NT*NV*NCIN, NB*NTM*NV*NCM, NKC, NC, NC, NC, NC, NC, NC};
    for (int i = 0; i < 9; ++i) {
        int n = pn[i];
        int blocks = (n + 255) / 256; if (blocks > 4096) blocks = 4096;
        k_convert<<<blocks, 256, 0, stream>>>(d_in[pidx[i]], p, n, flag);
        cp[pidx[i]] = p;
        p += (size_t)((n + 7) & ~7);
    }
    ush* w1t = p;   // [768][64]: q | k | v
    k_convT<<<64, 256, 0, stream>>>(d_in[4], w1t,          NCIN, NC, flag);
    k_convT<<<64, 256, 0, stream>>>(d_in[5], w1t + 16384,  NCIN, NC, flag);
    k_convT<<<64, 256, 0, stream>>>(d_in[6], w1t + 32768,  NCIN, NC, flag);
    p += 49152;
    ush* wq2t = p;  // [256][256]
    k_convT<<<256, 256, 0, stream>>>(d_in[9], wq2t, NC, NC, flag);
    p += 65536;
    ush* wkv2t = p; // [512][256]: k | v
    k_convT<<<256, 256, 0, stream>>>(d_in[10], wkv2t,         NCM, NC, flag);
    k_convT<<<256, 256, 0, stream>>>(d_in[11], wkv2t + 65536, NCM, NC, flag);
    p += 131072;
    ush* wgt = p;   // [768][256]
    k_convT<<<768, 256, 0, stream>>>(d_in[14], wgt, NC, NKC, flag);
    p += 196608;

    const int M = (int)NTOK;
    // stage 1: qkv1 = x @ [Wq1|Wk1|Wv1]  -> bufA [M,768]
    k_gemm<<<dim3(12, M / 128), 256, 0, stream>>>(cp[0], w1t, bufA, M, NCIN, NKC);
    k_attn_mfma<1><<<dim3(NV, NH, NB), 64, 0, stream>>>(bufA, bufB);
    k_ln<<<M / 4, 256, 0, stream>>>(bufB, cp[7], cp[8]);
    // stage 2: q2 = h1 @ Wq2 (cols 0-255); kv2 = m @ [Wk2|Wv2] (cols 256-767)
    k_gemm<<<dim3(4, M / 128), 256, 0, stream>>>(bufB, wq2t, bufA, M, NC, NKC);
    k_gemm<<<dim3(8, M / 128), 256, 0, stream>>>(cp[1], wkv2t, bufA + 256, M, NCM, NKC);
    k_attn_mfma<0><<<dim3(NV, NH, NB), 64, 0, stream>>>(bufA, bufB);
    k_ln<<<M / 4, 256, 0, stream>>>(bufB, cp[12], cp[13]);
    // stage 3: xw = h2 @ Wg -> bufA [M,768]; then GCN+LN -> out
    k_gemm<<<dim3(12, M / 128), 256, 0, stream>>>(bufB, wgt, bufA, M, NC, NKC);
    k_gcn<<<dim3(NT, NB), 256, 0, stream>>>(bufA, Af, cp[15], cp[16], cp[17], (float*)d_out);
}

// Round 7
// 334.529 us; speedup vs baseline: 8.5904x; 1.0415x over previous
//
#include <hip/hip_runtime.h>
#include <hip/hip_bf16.h>

typedef unsigned short ush;
typedef unsigned int uint32;
typedef __attribute__((ext_vector_type(8))) short s8v;   // 8 bf16 (4 VGPRs)
typedef __attribute__((ext_vector_type(4))) float f4v;   // MFMA accumulator

#define NB 16
#define NT 128
#define NTM 128
#define NV 25
#define NCIN 64
#define NCM 256
#define NH 8
#define ND 32
#define NC 256
#define NK 3
#define NKC 768
#define LN_EPS 1e-6f
#define QSCALE 0.17677669529663687f

__device__ __forceinline__ float bf2f(ush u) {
    union { uint32 i; float f; } x; x.i = ((uint32)u) << 16; return x.f;
}
__device__ __forceinline__ ush f2bf(float f) {
    union { float f; uint32 i; } x; x.f = f;
    uint32 r = x.i + 0x7FFFu + ((x.i >> 16) & 1u);
    return (ush)(r >> 16);
}

// -------- dtype detector (f32 vs bf16 device buffers) --------
__global__ __launch_bounds__(256) void k_detect(const uint32* __restrict__ xw,
                                               int* __restrict__ flag)
{
    __shared__ int cnt;
    if (threadIdx.x == 0) cnt = 0;
    __syncthreads();
    int c = 0;
    for (int i = 0; i < 4; ++i) {
        uint32 u = xw[threadIdx.x + 256 * i];
        uint32 e = (u >> 7) & 0xFF;
        c += (e >= 100 && e <= 135) ? 1 : 0;
    }
    atomicAdd(&cnt, c);
    __syncthreads();
    if (threadIdx.x == 0) *flag = (cnt > 700) ? 1 : 0;   // 1 = bf16, 0 = f32
}

// src (f32 or bf16) -> dst f32 (for A)
__global__ __launch_bounds__(256) void k_convF(const void* __restrict__ src,
                                               float* __restrict__ dst, int n,
                                               const int* __restrict__ flag)
{
    const bool isbf = (*flag != 0);
    int i = blockIdx.x * 256 + threadIdx.x;
    if (i < n) dst[i] = isbf ? bf2f(((const ush*)src)[i]) : ((const float*)src)[i];
}

// -------- single-launch converter: plain copies + [K,N]->[N,K] transposes --------
struct CvEnt { const void* src; ush* dst; int n; int K; int N; int blk0; };
struct CvTab { CvEnt e[16]; };

__global__ __launch_bounds__(256) void k_convall(CvTab tab, const int* __restrict__ flag)
{
    const bool isbf = (*flag != 0);
    const int bi = (int)blockIdx.x;
    int ei = 0;
    #pragma unroll
    for (int i = 1; i < 16; ++i) if (bi >= tab.e[i].blk0) ei = i;
    const CvEnt& e = tab.e[ei];
    const int idx = (bi - e.blk0) * 256 + (int)threadIdx.x;
    if (idx >= e.n) return;
    int s;
    if (e.K == 0) s = idx;
    else { int n = idx / e.K, k = idx - n * e.K; s = k * e.N + n; }
    e.dst[idx] = isbf ? ((const ush*)e.src)[s] : f2bf(((const float*)e.src)[s]);
}

// -------- MFMA GEMM: C[M, cols n0..] = A[M,K] @ Bt[N,K]^T --------
// BM=BN=128, BK=64, 4 waves (2x2), global_load_lds staging with pre-swizzled
// global source + linear LDS dest; XOR-swizzled ds_read_b128 fragment reads.
__global__ __launch_bounds__(256) void k_gemm(
    const ush* __restrict__ A, const ush* __restrict__ Bt, ush* __restrict__ C,
    int M, int K, int ldC)
{
    const int n0 = blockIdx.x * 128, m0 = blockIdx.y * 128;
    const int tid = threadIdx.x, w = tid >> 6, l = tid & 63;
    __shared__ ush As[8192], Bs[8192];   // 16KB each: 128 rows x 128B, linear
    const char* AsB = (const char*)As;
    const char* BsB = (const char*)Bs;
    const int rl = l >> 3, cc = l & 7;   // lane -> (row-in-8, 16B chunk)
    f4v acc[4][4] = {};
    const int wm = w >> 1, wn = w & 1;

    for (int kt = 0; kt < K; kt += 64) {
        __syncthreads();
        #pragma unroll
        for (int j = 0; j < 4; ++j) {
            const int r = (w * 4 + j) * 8 + rl;            // 0..127
            const int sc = (cc ^ (r & 7)) * 8;             // pre-swizzled k-chunk
            const ush* ga = &A[(size_t)(m0 + r) * K + kt + sc];
            const ush* gb = &Bt[(size_t)(n0 + r) * K + kt + sc];
            __builtin_amdgcn_global_load_lds(
                (const __attribute__((address_space(1))) uint32*)ga,
                (__attribute__((address_space(3))) uint32*)&As[(w * 4 + j) * 512], 16, 0, 0);
            __builtin_amdgcn_global_load_lds(
                (const __attribute__((address_space(1))) uint32*)gb,
                (__attribute__((address_space(3))) uint32*)&Bs[(w * 4 + j) * 512], 16, 0, 0);
        }
        __syncthreads();   // compiler drains vmcnt before barrier
        #pragma unroll
        for (int ks = 0; ks < 2; ++ks) {
            const int ko = ks * 64 + (l >> 4) * 16;        // byte offset in row
            s8v a[4], b[4];
            #pragma unroll
            for (int mi = 0; mi < 4; ++mi) {
                const int ra = wm * 64 + mi * 16 + (l & 15);
                a[mi] = *(const s8v*)(AsB + ra * 128 + (ko ^ ((ra & 7) << 4)));
            }
            #pragma unroll
            for (int ni = 0; ni < 4; ++ni) {
                const int rb = wn * 64 + ni * 16 + (l & 15);
                b[ni] = *(const s8v*)(BsB + rb * 128 + (ko ^ ((rb & 7) << 4)));
            }
            #pragma unroll
            for (int mi = 0; mi < 4; ++mi)
                #pragma unroll
                for (int ni = 0; ni < 4; ++ni)
                    acc[mi][ni] = __builtin_amdgcn_mfma_f32_16x16x32_bf16(a[mi], b[ni],
                                                                          acc[mi][ni], 0, 0, 0);
        }
    }
    const int col = n0 + wn * 64 + (l & 15);
    #pragma unroll
    for (int mi = 0; mi < 4; ++mi) {
        const int row_base = m0 + wm * 64 + mi * 16 + (l >> 4) * 4;
        #pragma unroll
        for (int ni = 0; ni < 4; ++ni)
            #pragma unroll
            for (int r = 0; r < 4; ++r)
                C[(size_t)(row_base + r) * ldC + col + ni * 16] = f2bf(acc[mi][ni][r]);
    }
}

// -------- MFMA attention: 1 wave = 1 (b,h,v) head; zero LDS --------
template<int MASKED>
__global__ __launch_bounds__(64) void k_attn_mfma(
    const ush* __restrict__ QKV, ush* __restrict__ O)
{
    const int v = blockIdx.x, h = blockIdx.y, b = blockIdx.z;
    const int l = threadIdx.x, g = l >> 4, c = l & 15;
    const size_t tokStride = (size_t)NV * NKC;
    const ush* base = QKV + ((size_t)b * NT * NV + v) * NKC;

    s8v kf[8];
    const int koff = 256 + h * ND + g * 8;
    #pragma unroll
    for (int si = 0; si < 8; ++si)
        kf[si] = *(const s8v*)(base + (size_t)(16 * si + c) * tokStride + koff);

    s8v vf[4][2];
    #pragma unroll
    for (int ks = 0; ks < 4; ++ks)
        #pragma unroll
        for (int ni = 0; ni < 2; ++ni) {
            const int voff = 512 + h * ND + 16 * ni + c;
            s8v tmp;
            #pragma unroll
            for (int j = 0; j < 8; ++j)
                tmp[j] = (short)base[(size_t)(32 * ks + 8 * g + j) * tokStride + voff];
            vf[ks][ni] = tmp;
        }

    ush* og = O + ((size_t)b * NT * NV + v) * NC + h * ND;
    const int qoff = h * ND + g * 8;
    const int ga = (g & 1) * 2;
    const int l1 = ga * 16 + c, l2 = l1 + 16;
    const bool hisel = (g >> 1) != 0;

    for (int t16 = 0; t16 < 8; ++t16) {
        s8v qf = *(const s8v*)(base + (size_t)(16 * t16 + c) * tokStride + qoff);
        f4v st[8];
        #pragma unroll
        for (int si = 0; si < 8; ++si)
            st[si] = __builtin_amdgcn_mfma_f32_16x16x32_bf16(kf[si], qf,
                                                             (f4v){0.f, 0.f, 0.f, 0.f}, 0, 0, 0);
        const int t = 16 * t16 + c;
        if (MASKED) {
            #pragma unroll
            for (int si = 0; si < 8; ++si)
                #pragma unroll
                for (int r = 0; r < 4; ++r)
                    if (16 * si + 4 * g + r > t) st[si][r] = -1e30f;
        }
        float mx = -1e30f;
        #pragma unroll
        for (int si = 0; si < 8; ++si)
            #pragma unroll
            for (int r = 0; r < 4; ++r) mx = fmaxf(mx, st[si][r]);
        mx = fmaxf(mx, __shfl_xor(mx, 16));
        mx = fmaxf(mx, __shfl_xor(mx, 32));
        float sm = 0.f;
        #pragma unroll
        for (int si = 0; si < 8; ++si)
            #pragma unroll
            for (int r = 0; r < 4; ++r) {
                float e = __expf((st[si][r] - mx) * QSCALE);
                st[si][r] = e;
                sm += e;
            }
        sm += __shfl_xor(sm, 16);
        sm += __shfl_xor(sm, 32);
        const float inv = 1.f / sm;
        uint32 u[8][2];
        #pragma unroll
        for (int si = 0; si < 8; ++si) {
            float e0 = st[si][0] * inv, e1 = st[si][1] * inv;
            float e2 = st[si][2] * inv, e3 = st[si][3] * inv;
            asm("v_cvt_pk_bf16_f32 %0, %1, %2" : "=v"(u[si][0]) : "v"(e0), "v"(e1));
            asm("v_cvt_pk_bf16_f32 %0, %1, %2" : "=v"(u[si][1]) : "v"(e2), "v"(e3));
        }
        f4v o[2] = {};
        #pragma unroll
        for (int ks = 0; ks < 4; ++ks) {
            uint32 w0a = __shfl(u[2 * ks][0], l1),     w0b = __shfl(u[2 * ks][1], l1);
            uint32 w0c = __shfl(u[2 * ks][0], l2),     w0d = __shfl(u[2 * ks][1], l2);
            uint32 w1a = __shfl(u[2 * ks + 1][0], l1), w1b = __shfl(u[2 * ks + 1][1], l1);
            uint32 w1c = __shfl(u[2 * ks + 1][0], l2), w1d = __shfl(u[2 * ks + 1][1], l2);
            union { uint32 w[4]; s8v s; } pa;
            pa.w[0] = hisel ? w1a : w0a;
            pa.w[1] = hisel ? w1b : w0b;
            pa.w[2] = hisel ? w1c : w0c;
            pa.w[3] = hisel ? w1d : w0d;
            o[0] = __builtin_amdgcn_mfma_f32_16x16x32_bf16(pa.s, vf[ks][0], o[0], 0, 0, 0);
            o[1] = __builtin_amdgcn_mfma_f32_16x16x32_bf16(pa.s, vf[ks][1], o[1], 0, 0, 0);
        }
        #pragma unroll
        for (int ni = 0; ni < 2; ++ni)
            #pragma unroll
            for (int r = 0; r < 4; ++r)
                og[(size_t)(16 * t16 + 4 * g + r) * (NV * NC) + 16 * ni + c] = f2bf(o[ni][r]);
    }
}

// ---------------- row LayerNorm (unbiased std), in place, 1 wave = 1 row ----------------
__global__ __launch_bounds__(256) void k_ln(
    ush* __restrict__ buf, const ush* __restrict__ g, const ush* __restrict__ bb)
{
    const int row = blockIdx.x * 4 + (threadIdx.x >> 6);
    const int lane = threadIdx.x & 63;
    ush* p = buf + (size_t)row * NC + lane * 4;
    uint2 u = *(uint2*)p;
    float x0 = bf2f((ush)(u.x & 0xffff)), x1 = bf2f((ush)(u.x >> 16));
    float x2 = bf2f((ush)(u.y & 0xffff)), x3 = bf2f((ush)(u.y >> 16));
    float s = x0 + x1 + x2 + x3;
    float q = x0 * x0 + x1 * x1 + x2 * x2 + x3 * x3;
    #pragma unroll
    for (int o = 32; o; o >>= 1) { s += __shfl_xor(s, o); q += __shfl_xor(q, o); }
    float mean = s * (1.f / 256.f);
    float var = fmaxf((q - 256.f * mean * mean) * (1.f / 255.f), 0.f);
    float inv = 1.f / (sqrtf(var) + LN_EPS);
    float o0 = bf2f(g[lane * 4 + 0]) * (x0 - mean) * inv + bf2f(bb[lane * 4 + 0]);
    float o1 = bf2f(g[lane * 4 + 1]) * (x1 - mean) * inv + bf2f(bb[lane * 4 + 1]);
    float o2 = bf2f(g[lane * 4 + 2]) * (x2 - mean) * inv + bf2f(bb[lane * 4 + 2]);
    float o3 = bf2f(g[lane * 4 + 3]) * (x3 - mean) * inv + bf2f(bb[lane * 4 + 3]);
    uint32 lo = (uint32)f2bf(o0) | ((uint32)f2bf(o1) << 16);
    uint32 hi = (uint32)f2bf(o2) | ((uint32)f2bf(o3) << 16);
    *(uint2*)p = make_uint2(lo, hi);
}

// -------- GCN contraction + bias + LayerNorm; LDS-staged xw tile --------
__global__ __launch_bounds__(256) void k_gcn(
    const ush* __restrict__ xw, const float* __restrict__ Af,
    const ush* __restrict__ bg, const ush* __restrict__ g3, const ush* __restrict__ b3,
    float* __restrict__ outp)
{
    const int t = blockIdx.x, b = blockIdx.y;
    const int tid = threadIdx.x;
    __shared__ ush xs[NV * NKC];     // 38.4KB, coalesced uint4 staging
    __shared__ float h3s[NV * NC];   // 25.6KB
    __shared__ float cs[80];

    const ush* xr = xw + ((size_t)(b * NT + t)) * NV * NKC;
    for (int i = tid; i < NV * NKC / 8; i += 256)
        *(uint4*)&xs[i * 8] = *(const uint4*)&xr[i * 8];
    if (tid < 75) {
        int k = tid / 25, w = tid - k * 25;
        float s = 0.f;
        #pragma unroll
        for (int v = 0; v < NV; ++v) s += Af[k * 625 + v * 25 + w];
        cs[tid] = s;
    }
    __syncthreads();
    float xv[75];
    #pragma unroll
    for (int v = 0; v < NV; ++v)
        #pragma unroll
        for (int k = 0; k < NK; ++k)
            xv[v * 3 + k] = bf2f(xs[v * NKC + k * NC + tid]);
    float bgv[3];
    #pragma unroll
    for (int k = 0; k < NK; ++k) bgv[k] = bf2f(bg[k * NC + tid]);
    for (int w = 0; w < NV; ++w) {
        float a = bgv[0] * cs[w] + bgv[1] * cs[25 + w] + bgv[2] * cs[50 + w];
        #pragma unroll
        for (int k = 0; k < NK; ++k)
            #pragma unroll
            for (int v = 0; v < NV; ++v)
                a += Af[k * 625 + v * 25 + w] * xv[v * 3 + k];   // uniform -> s_load
        h3s[w * NC + tid] = a;
    }
    __syncthreads();
    {
        const int wv = tid >> 6, lane = tid & 63;
        for (int w = wv; w < NV; w += 4) {
            float x0 = h3s[w * NC + lane * 4 + 0];
            float x1 = h3s[w * NC + lane * 4 + 1];
            float x2 = h3s[w * NC + lane * 4 + 2];
            float x3 = h3s[w * NC + lane * 4 + 3];
            float s = x0 + x1 + x2 + x3;
            float q = x0 * x0 + x1 * x1 + x2 * x2 + x3 * x3;
            #pragma unroll
            for (int o = 32; o; o >>= 1) { s += __shfl_xor(s, o); q += __shfl_xor(q, o); }
            float mean = s * (1.f / 256.f);
            float var = fmaxf((q - 256.f * mean * mean) * (1.f / 255.f), 0.f);
            float inv = 1.f / (sqrtf(var) + LN_EPS);
            float o0 = bf2f(g3[lane * 4 + 0]) * (x0 - mean) * inv + bf2f(b3[lane * 4 + 0]);
            float o1 = bf2f(g3[lane * 4 + 1]) * (x1 - mean) * inv + bf2f(b3[lane * 4 + 1]);
            float o2 = bf2f(g3[lane * 4 + 2]) * (x2 - mean) * inv + bf2f(b3[lane * 4 + 2]);
            float o3 = bf2f(g3[lane * 4 + 3]) * (x3 - mean) * inv + bf2f(b3[lane * 4 + 3]);
            float* op = outp + (((size_t)(b * NT + t)) * NV + w) * NC + lane * 4;
            *(float4*)op = make_float4(o0, o1, o2, o3);
        }
    }
}

extern "C" void kernel_launch(void* const* d_in, const int* in_sizes, int n_in,
                              void* d_out, int out_size, void* d_ws, size_t ws_size,
                              hipStream_t stream)
{
    const size_t NTOK = (size_t)NB * NT * NV;   // 51200
    char* ws = (char*)d_ws;
    int* flag = (int*)ws;
    float* Af = (float*)(ws + 256);             // A as f32, 7.5KB
    ush* bufA = (ush*)(ws + 8192);              // [M,768]  78.6MB
    ush* bufB = bufA + NTOK * NKC;              // [M,256]  26.2MB
    ush* conv = bufB + NTOK * NC;

    k_detect<<<1, 256, 0, stream>>>((const uint32*)d_in[0], flag);
    k_convF<<<8, 256, 0, stream>>>(d_in[2], Af, NK * NV * NV, flag);

    // ---- one-launch conversion table ----
    CvTab tab;
    int nent = 0, blk = 0;
    ush* p = conv;
    const ush* cp[18] = {};
    auto add = [&](int idx, int n, int K, int N, ush*& dst_out) {
        tab.e[nent] = { d_in[idx], p, n, K, N, blk };
        dst_out = p;
        blk += (n + 255) / 256;
        p += (size_t)((n + 7) & ~7);
        ++nent;
    };
    ush* d;
    add(0, NB * NT * NV * NCIN, 0, 0, d);  cp[0] = d;
    add(1, NB * NTM * NV * NCM, 0, 0, d);  cp[1] = d;
    add(15, NKC, 0, 0, d);                 cp[15] = d;
    add(7, NC, 0, 0, d);  cp[7] = d;
    add(8, NC, 0, 0, d);  cp[8] = d;
    add(12, NC, 0, 0, d); cp[12] = d;
    add(13, NC, 0, 0, d); cp[13] = d;
    add(16, NC, 0, 0, d); cp[16] = d;
    add(17, NC, 0, 0, d); cp[17] = d;
    ush* w1t;
    add(4, NCIN * NC, NCIN, NC, w1t);      // [256][64] q
    add(5, NCIN * NC, NCIN, NC, d);        // k  (contiguous after q)
    add(6, NCIN * NC, NCIN, NC, d);        // v
    ush* wq2t;
    add(9, NC * NC, NC, NC, wq2t);         // [256][256]
    ush* wkv2t;
    add(10, NCM * NC, NCM, NC, wkv2t);     // [256][256] k
    add(11, NCM * NC, NCM, NC, d);         // v (contiguous)
    ush* wgt;
    add(14, NC * NKC, NC, NKC, wgt);       // [768][256]
    k_convall<<<blk, 256, 0, stream>>>(tab, flag);

    const int M = (int)NTOK;
    // stage 1: qkv1 = x @ [Wq1|Wk1|Wv1]  -> bufA [M,768]
    k_gemm<<<dim3(6, M / 128), 256, 0, stream>>>(cp[0], w1t, bufA, M, NCIN, NKC);
    k_attn_mfma<1><<<dim3(NV, NH, NB), 64, 0, stream>>>(bufA, bufB);
    k_ln<<<M / 4, 256, 0, stream>>>(bufB, cp[7], cp[8]);
    // stage 2: q2 = h1 @ Wq2 (cols 0-255); kv2 = m @ [Wk2|Wv2] (cols 256-767)
    k_gemm<<<dim3(2, M / 128), 256, 0, stream>>>(bufB, wq2t, bufA, M, NC, NKC);
    k_gemm<<<dim3(4, M / 128), 256, 0, stream>>>(cp[1], wkv2t, bufA + 256, M, NCM, NKC);
    k_attn_mfma<0><<<dim3(NV, NH, NB), 64, 0, stream>>>(bufA, bufB);
    k_ln<<<M / 4, 256, 0, stream>>>(bufB, cp[12], cp[13]);
    // stage 3: xw = h2 @ Wg -> bufA [M,768]; then GCN+LN -> out
    k_gemm<<<dim3(6, M / 128), 256, 0, stream>>>(bufB, wgt, bufA, M, NC, NKC);
    k_gcn<<<dim3(NT, NB), 256, 0, stream>>>(bufA, Af, cp[15], cp[16], cp[17], (float*)d_out);
}